// Round 6
// baseline (410.152 us; speedup 1.0000x reference)
//
#include <hip/hip_runtime.h>
#include <hip/hip_bf16.h>

#define E_TOT 160000
#define NN    10000
#define EPB   32      // edges per block

typedef unsigned short ushortT;
typedef unsigned int   uintT;
typedef __attribute__((ext_vector_type(8))) short short8;
typedef __attribute__((ext_vector_type(4))) float f32x4;

__device__ __forceinline__ float sigmoidf_(float x) { return 1.0f / (1.0f + __expf(-x)); }
__device__ __forceinline__ float siluf_(float x) { return x * sigmoidf_(x); }

__device__ __forceinline__ ushortT f2b(float f) {
    union { float f; uintT u; } x; x.f = f;
    uintT r = x.u + 0x7fffu + ((x.u >> 16) & 1u);
    return (ushortT)(r >> 16);
}
__device__ __forceinline__ float b2f(ushortT h) {
    union { uintT u; float f; } x; x.u = ((uintT)h) << 16; return x.f;
}
__device__ __forceinline__ uintT pk2(float lo, float hi) {
    union { __hip_bfloat162 h; uintT u; } cv;
    cv.h = __float22bfloat162_rn(make_float2(lo, hi));
    return cv.u;
}
// 8 consecutive fp32 -> bf16 MFMA A-fragment
__device__ __forceinline__ short8 ldfrag(const float* p) {
    const float4 x = ((const float4*)p)[0];
    const float4 y = ((const float4*)p)[1];
    union { uintT u[4]; short8 s; } r;
    r.u[0] = pk2(x.x, x.y); r.u[1] = pk2(x.z, x.w);
    r.u[2] = pk2(y.x, y.y); r.u[3] = pk2(y.z, y.w);
    return r.s;
}

// ---- workspace layout (ushort offsets) ----
#define OFF_W1SO 0
#define OFF_W2SO 45056
#define OFF_W1DF 65536
#define OFF_W1G  68608
#define OFF_W1UP 70656
#define OFF_W2DF 71680
#define OFF_W2G  72704
#define OFF_W2UP 74752
// total 75264 ushorts

__global__ __launch_bounds__(256) void prep_kernel(
    const float* __restrict__ W1so, const float* __restrict__ W2so,
    const float* __restrict__ W1d,  const float* __restrict__ W1f,
    const float* __restrict__ W1g,  const float* __restrict__ W1up,
    const float* __restrict__ W2d,  const float* __restrict__ W2f,
    const float* __restrict__ W2g,  const float* __restrict__ W2up,
    ushortT* __restrict__ ws, float* __restrict__ out)
{
    int i = blockIdx.x * 256 + threadIdx.x;    // grid 294*256 = 75264 exactly
    float4* o4 = (float4*)out;                 // zero d_out: 440,000 float4
    #pragma unroll
    for (int k = 0; k < 6; ++k) {
        int z = i + k * 75264;
        if (z < 440000) o4[z] = make_float4(0.f, 0.f, 0.f, 0.f);
    }
    if (i < OFF_W2SO) {                        // W1soT [n=128][k=352], k<333 real
        int n = i / 352, k = i - n * 352;
        ws[i] = (k < 333) ? f2b(W1so[k * 128 + n]) : (ushortT)0;
    } else if (i < OFF_W1DF) {                 // W2soT [128][160], k<153 real
        int j = i - OFF_W2SO, n = j / 160, k = j - n * 160;
        ws[i] = (k < 153) ? f2b(W2so[k * 128 + n]) : (ushortT)0;
    } else if (i < OFF_W1G) {                  // W1dfT [48][64]: n<36 Wd, 36..38 Wf
        int j = i - OFF_W1DF, n = j / 64, k = j - n * 64;
        float v = 0.f;
        if (k < 36) { if (n < 36) v = W1d[k * 36 + n]; else if (n < 39) v = W1f[k * 3 + (n - 36)]; }
        ws[i] = f2b(v);
    } else if (i < OFF_W1UP) {                 // W1gT [16][128]
        int j = i - OFF_W1G, n = j / 128, k = j - n * 128;
        ws[i] = f2b(W1g[k * 16 + n]);
    } else if (i < OFF_W2DF) {                 // W1upT [16][64], k<36 real
        int j = i - OFF_W1UP, n = j / 64, k = j - n * 64;
        ws[i] = (k < 36) ? f2b(W1up[k * 16 + n]) : (ushortT)0;
    } else if (i < OFF_W2G) {                  // W2dfT [32][32]: n<16 Wd, 16..18 Wf; k<16
        int j = i - OFF_W2DF, n = j / 32, k = j - n * 32;
        float v = 0.f;
        if (k < 16) { if (n < 16) v = W2d[k * 16 + n]; else if (n < 19) v = W2f[k * 3 + (n - 16)]; }
        ws[i] = f2b(v);
    } else if (i < OFF_W2UP) {                 // W2gT [16][128]
        int j = i - OFF_W2G, n = j / 128, k = j - n * 128;
        ws[i] = f2b(W2g[k * 16 + n]);
    } else {                                   // W2upT [16][32], k<16 real
        int j = i - OFF_W2UP, n = j / 32, k = j - n * 32;
        ws[i] = (k < 16) ? f2b(W2up[k * 16 + n]) : (ushortT)0;
    }
}

#define MFMA(a, b, c) __builtin_amdgcn_mfma_f32_16x16x32_bf16((a), (b), (c), 0, 0, 0)

// LDS 31,104 B -> 5 blocks/CU (20 waves). 8 barriers. Wave-local gates.
__global__ __launch_bounds__(256, 5) void edge_kernel(
    const float* __restrict__ node_s, const float* __restrict__ node_v,
    const float* __restrict__ edge_s, const float* __restrict__ edge_v,
    const float* __restrict__ frames,
    const float* __restrict__ b1so, const float* __restrict__ b1g,
    const float* __restrict__ b2so, const float* __restrict__ b2g,
    const float* __restrict__ attW, const float* __restrict__ attb,
    const ushortT* __restrict__ wsc,
    const void* __restrict__ eidx, float* __restrict__ out)
{
    const ushortT* W1T   = wsc + OFF_W1SO;
    const ushortT* W2T   = wsc + OFF_W2SO;
    const ushortT* W1dfT = wsc + OFF_W1DF;
    const ushortT* W1gT  = wsc + OFF_W1G;
    const ushortT* W1upT = wsc + OFF_W1UP;
    const ushortT* W2dfT = wsc + OFF_W2DF;
    const ushortT* W2gT  = wsc + OFF_W2G;
    const ushortT* W2upT = wsc + OFF_W2UP;

    // ---- LDS overlay map (bytes), total 31104 ----
    // P [0..10752):     mvA bf16[96][40] (A->B)      | m2 bf16[32][168] (D->L)
    // Q [10752..19456): vhidA bf16[96][40] (B->E2)   | s2s bf16[32][136] (I->L)
    // R [19456..29824): normbuf bf16[32][72] (A..C->D) |
    //                   v1A bf16[96][24] @19456 (E->L), vhid2A bf16[96][24] @24064 (G->J2/H),
    //                   vfr2f f32[96][3] @28672 (G->H)
    // fr f32[32][9] @29824, attn f32[32] @30976
    __shared__ __align__(16) char smem[31104];
    ushortT* mvA     = (ushortT*)smem;
    ushortT* m2      = (ushortT*)smem;
    ushortT* vhidA   = (ushortT*)(smem + 10752);
    ushortT* s2s     = (ushortT*)(smem + 10752);
    ushortT* normbuf = (ushortT*)(smem + 19456);
    ushortT* v1A     = (ushortT*)(smem + 19456);
    ushortT* vhid2A  = (ushortT*)(smem + 24064);
    float*   vfr2f   = (float*)(smem + 28672);
    float*   fr      = (float*)(smem + 29824);
    float*   attn    = (float*)(smem + 30976);

    const int t  = threadIdx.x;
    const int eg = blockIdx.x * EPB;
    const int w  = t >> 6, lane = t & 63, lq = lane >> 4, ln = lane & 15;
    const int te = t >> 3, tj = t & 7;     // 8 threads per edge
    const int p  = w & 1;                  // edge-tile parity owned by this wave

    const int* pi = (const int*)eidx;
    const long long* pl = (const long long*)eidx;
    const bool is64 = ((pi[1] | pi[3] | pi[5] | pi[7] |
                        pi[9] | pi[11] | pi[13] | pi[15]) == 0);

    // ==== Phase A: gathers + pads ====
    {
        const int nr = is64 ? (int)pl[eg + te] : pi[eg + te];
        const int nc = is64 ? (int)pl[E_TOT + eg + te] : pi[E_TOT + eg + te];
        const int nvr = nr * 48, nvc = nc * 48, evb = (eg + te) * 12;
        #pragma unroll
        for (int k = 0; k < 14; ++k) {          // 108 vector elems per edge
            int r = tj + k * 8;
            if (r < 108) {
                float v;
                if (r < 48)      v = node_v[nvr + r];
                else if (r < 60) v = edge_v[evb + (r - 48)];
                else             v = node_v[nvc + (r - 60)];
                int c = r / 3, sp = r - c * 3;
                mvA[(sp * 32 + te) * 40 + c] = f2b(v);
            }
        }
        #pragma unroll
        for (int k = 0; k < 2; ++k) {           // frames: 9 per edge
            int j = tj + k * 8;
            if (j < 9) fr[te * 9 + j] = frames[(eg + te) * 9 + j];
        }
        #pragma unroll
        for (int k = 0; k < 3; ++k) {           // normbuf cols 45..63 = 0
            int c = 45 + tj + k * 8;
            if (c < 64) normbuf[te * 72 + c] = 0;
        }
        if (t < 192) {                          // mvA cols 36..39 = 0 (finite-pad)
            int r = t >> 1, cc = 36 + ((t & 1) << 1);
            *(uintT*)(mvA + r * 40 + cc) = 0;
        }
    }
    __syncthreads();   // (1)

    // ==== Phase B: mvA[96xK36] @ W1dfT[48][64] -> vhidA[96][<=40] ====
    for (int u = w; u < 18; u += 4) {
        int mt = u / 3, nt = u - mt * 3;
        const ushortT* ap = mvA + (mt * 16 + ln) * 40 + lq * 8;
        const ushortT* bp = W1dfT + (nt * 16 + ln) * 64 + lq * 8;
        f32x4 acc = {0.f, 0.f, 0.f, 0.f};
        acc = MFMA(*(const short8*)ap, *(const short8*)bp, acc);
        short8 a2 = {0, 0, 0, 0, 0, 0, 0, 0};
        if (lq == 0) a2 = *(const short8*)(ap + 32);
        acc = MFMA(a2, *(const short8*)(bp + 32), acc);
        if (nt < 2 || ln < 8) {
            ushortT* op = vhidA + (mt * 16 + lq * 4) * 40 + nt * 16 + ln;
            op[0]   = f2b(acc[0]); op[40]  = f2b(acc[1]);
            op[80]  = f2b(acc[2]); op[120] = f2b(acc[3]);
        }
    }
    __syncthreads();   // (2)

    // ==== Phase C: v_norm1 + local1 -> normbuf cols 0..44 ====
    {
        #pragma unroll
        for (int k = 0; k < 5; ++k) {
            int h = tj + k * 8;
            if (h < 36) {
                float a0 = b2f(vhidA[te * 40 + h]);
                float a1 = b2f(vhidA[(32 + te) * 40 + h]);
                float a2 = b2f(vhidA[(64 + te) * 40 + h]);
                normbuf[te * 72 + h] = f2b(sqrtf(fmaf(a0, a0, fmaf(a1, a1, fmaf(a2, a2, 1e-8f)))));
            }
        }
        for (int i = t; i < 288; i += 256) {
            int e = i / 9, r = i - e * 9, a = r / 3, b = r - a * 3;
            float x = fr[e * 9 + b * 3 + 0] * b2f(vhidA[e * 40 + 36 + a])
                    + fr[e * 9 + b * 3 + 1] * b2f(vhidA[(32 + e) * 40 + 36 + a])
                    + fr[e * 9 + b * 3 + 2] * b2f(vhidA[(64 + e) * 40 + 36 + a]);
            normbuf[e * 72 + 36 + r] = f2b(x);
        }
    }
    __syncthreads();   // (3)

    // ==== Phase D: s_out1 — A direct from global (k<288) + normbuf (k 288..351) ====
    {
        const int klq = lq * 8;
        const int e0 = ln, e1 = 16 + ln;
        int r0, c0, r1, c1;
        if (is64) {
            r0 = (int)pl[eg + e0]; r1 = (int)pl[eg + e1];
            c0 = (int)pl[E_TOT + eg + e0]; c1 = (int)pl[E_TOT + eg + e1];
        } else {
            r0 = pi[eg + e0]; r1 = pi[eg + e1];
            c0 = pi[E_TOT + eg + e0]; c1 = pi[E_TOT + eg + e1];
        }
        r0 *= 128; c0 *= 128; r1 *= 128; c1 *= 128;
        const int eb0 = (eg + e0) * 32, eb1 = (eg + e1) * 32;
        f32x4 acc00 = {0,0,0,0}, acc01 = {0,0,0,0}, acc10 = {0,0,0,0}, acc11 = {0,0,0,0};
        const ushortT* b0p = W1T + (w * 32 + ln) * 352 + klq;
        const ushortT* b1p = W1T + (w * 32 + 16 + ln) * 352 + klq;
        #pragma unroll
        for (int ks = 0; ks < 9; ++ks) {
            const float *pa0, *pa1;
            if (ks < 4)       { pa0 = node_s + r0 + ks * 32 + klq;        pa1 = node_s + r1 + ks * 32 + klq; }
            else if (ks == 4) { pa0 = edge_s + eb0 + klq;                 pa1 = edge_s + eb1 + klq; }
            else              { pa0 = node_s + c0 + (ks - 5) * 32 + klq;  pa1 = node_s + c1 + (ks - 5) * 32 + klq; }
            short8 a0 = ldfrag(pa0);
            short8 a1 = ldfrag(pa1);
            short8 b0 = *(const short8*)(b0p + ks * 32);
            short8 b1 = *(const short8*)(b1p + ks * 32);
            acc00 = MFMA(a0, b0, acc00); acc01 = MFMA(a0, b1, acc01);
            acc10 = MFMA(a1, b0, acc10); acc11 = MFMA(a1, b1, acc11);
        }
        #pragma unroll
        for (int ks = 9; ks < 11; ++ks) {
            short8 a0 = *(const short8*)(normbuf + e0 * 72 + (ks - 9) * 32 + klq);
            short8 a1 = *(const short8*)(normbuf + e1 * 72 + (ks - 9) * 32 + klq);
            short8 b0 = *(const short8*)(b0p + ks * 32);
            short8 b1 = *(const short8*)(b1p + ks * 32);
            acc00 = MFMA(a0, b0, acc00); acc01 = MFMA(a0, b1, acc01);
            acc10 = MFMA(a1, b0, acc10); acc11 = MFMA(a1, b1, acc11);
        }
        const int n0 = w * 32 + ln, n1 = n0 + 16;
        float bi0 = b1so[n0], bi1 = b1so[n1];
        #pragma unroll
        for (int r = 0; r < 4; ++r) {
            int m0 = lq * 4 + r;
            m2[m0 * 168 + n0]        = f2b(siluf_(acc00[r] + bi0));
            m2[m0 * 168 + n1]        = f2b(siluf_(acc01[r] + bi1));
            m2[(16 + m0) * 168 + n0] = f2b(siluf_(acc10[r] + bi0));
            m2[(16 + m0) * 168 + n1] = f2b(siluf_(acc11[r] + bi1));
        }
    }
    __syncthreads();   // (4)

    // ==== Phase E+G (barrier-free stretch, wave-local) ====
    {
        // gate1 for this wave's edge-tile parity p: C-fragment aligns with E2's
        f32x4 gacc = {0,0,0,0};
        {
            const ushortT* ap = m2 + (p * 16 + ln) * 168;
            const ushortT* bp = W1gT + ln * 128;
            #pragma unroll
            for (int ks = 0; ks < 4; ++ks)
                gacc = MFMA(*(const short8*)(ap + ks * 32 + lq * 8),
                            *(const short8*)(bp + ks * 32 + lq * 8), gacc);
        }
        float g1[4];
        {
            float bi = b1g[ln];
            #pragma unroll
            for (int r = 0; r < 4; ++r) g1[r] = sigmoidf_(gacc[r] + bi);
        }
        // E2: raw v1 for owned M-tiles (mt = w, and w+4 if w<2)
        const ushortT* bpu = W1upT + ln * 64 + lq * 8;
        short8 bu1 = *(const short8*)bpu;
        short8 bu2 = *(const short8*)(bpu + 32);
        #pragma unroll
        for (int c = 0; c < 2; ++c) {
            if (c == 1 && w >= 2) break;
            int mt = w + c * 4;
            const ushortT* ap = vhidA + (mt * 16 + ln) * 40 + lq * 8;
            f32x4 acc = {0,0,0,0};
            acc = MFMA(*(const short8*)ap, bu1, acc);
            short8 a2 = {0, 0, 0, 0, 0, 0, 0, 0};
            if (lq == 0) a2 = *(const short8*)(ap + 32);
            acc = MFMA(a2, bu2, acc);
            #pragma unroll
            for (int r = 0; r < 4; ++r) {
                int row = mt * 16 + lq * 4 + r;
                v1A[row * 24 + ln] = f2b(acc[r] * g1[r]);
            }
        }
        // G: vhid2/vfr2 for owned tiles (reads v1A just written by this wave)
        #pragma unroll
        for (int c = 0; c < 2; ++c) {
            if (c == 1 && w >= 2) break;
            int mt = w + c * 4;
            const ushortT* ap = v1A + (mt * 16 + ln) * 24 + lq * 8;
            short8 a = {0, 0, 0, 0, 0, 0, 0, 0};
            if (lq < 2) a = *(const short8*)ap;
            #pragma unroll
            for (int nt = 0; nt < 2; ++nt) {
                const ushortT* bp = W2dfT + (nt * 16 + ln) * 32 + lq * 8;
                f32x4 acc = {0,0,0,0};
                acc = MFMA(a, *(const short8*)bp, acc);
                if (nt == 0) {
                    ushortT* op = vhid2A + (mt * 16 + lq * 4) * 24 + ln;
                    op[0]  = f2b(acc[0]); op[24] = f2b(acc[1]);
                    op[48] = f2b(acc[2]); op[72] = f2b(acc[3]);
                } else if (ln < 3) {
                    float* op = vfr2f + (mt * 16 + lq * 4) * 3 + ln;
                    op[0] = acc[0]; op[3] = acc[1]; op[6] = acc[2]; op[9] = acc[3];
                }
            }
        }
    }
    __syncthreads();   // (5)

    // ==== Phase H: norm2 + local2 + zero pad into m2 cols 128..159 ====
    {
        #pragma unroll
        for (int k = 0; k < 2; ++k) {
            int i = t + k * 256, e = i >> 4, h = i & 15;
            float a0 = b2f(vhid2A[e * 24 + h]);
            float a1 = b2f(vhid2A[(32 + e) * 24 + h]);
            float a2 = b2f(vhid2A[(64 + e) * 24 + h]);
            m2[e * 168 + 128 + h] = f2b(sqrtf(fmaf(a0, a0, fmaf(a1, a1, fmaf(a2, a2, 1e-8f)))));
        }
        for (int i = t; i < 288; i += 256) {
            int e = i / 9, r = i - e * 9, a = r / 3, b = r - a * 3;
            float x = fr[e * 9 + b * 3 + 0] * vfr2f[e * 3 + a]
                    + fr[e * 9 + b * 3 + 1] * vfr2f[(32 + e) * 3 + a]
                    + fr[e * 9 + b * 3 + 2] * vfr2f[(64 + e) * 3 + a];
            m2[e * 168 + 144 + r] = f2b(x);
        }
        if (tj) m2[te * 168 + 152 + tj] = 0;    // cols 153..159 = 0
    }
    __syncthreads();   // (6)

    // ==== Phase I: s_out2 = m2[32][160] @ W2soT -> s2s (silu) ====
    {
        f32x4 acc00 = {0,0,0,0}, acc01 = {0,0,0,0}, acc10 = {0,0,0,0}, acc11 = {0,0,0,0};
        const ushortT* a0p = m2 + ln * 168 + lq * 8;
        const ushortT* a1p = m2 + (16 + ln) * 168 + lq * 8;
        const ushortT* b0p = W2T + (w * 32 + ln) * 160 + lq * 8;
        const ushortT* b1p = W2T + (w * 32 + 16 + ln) * 160 + lq * 8;
        #pragma unroll
        for (int ks = 0; ks < 5; ++ks) {
            short8 a0 = *(const short8*)(a0p + ks * 32);
            short8 a1 = *(const short8*)(a1p + ks * 32);
            short8 b0 = *(const short8*)(b0p + ks * 32);
            short8 b1 = *(const short8*)(b1p + ks * 32);
            acc00 = MFMA(a0, b0, acc00); acc01 = MFMA(a0, b1, acc01);
            acc10 = MFMA(a1, b0, acc10); acc11 = MFMA(a1, b1, acc11);
        }
        const int n0 = w * 32 + ln, n1 = n0 + 16;
        float bi0 = b2so[n0], bi1 = b2so[n1];
        #pragma unroll
        for (int r = 0; r < 4; ++r) {
            int m0 = lq * 4 + r;
            s2s[m0 * 136 + n0]        = f2b(siluf_(acc00[r] + bi0));
            s2s[m0 * 136 + n1]        = f2b(siluf_(acc01[r] + bi1));
            s2s[(16 + m0) * 136 + n0] = f2b(siluf_(acc10[r] + bi0));
            s2s[(16 + m0) * 136 + n1] = f2b(siluf_(acc11[r] + bi1));
        }
    }
    __syncthreads();   // (7)

    // ==== Phase J (wave-local) + attention ====
    {
        f32x4 gacc = {0,0,0,0};
        {
            const ushortT* ap = s2s + (p * 16 + ln) * 136;
            const ushortT* bp = W2gT + ln * 128;
            #pragma unroll
            for (int ks = 0; ks < 4; ++ks)
                gacc = MFMA(*(const short8*)(ap + ks * 32 + lq * 8),
                            *(const short8*)(bp + ks * 32 + lq * 8), gacc);
        }
        float g2[4];
        {
            float bi = b2g[ln];
            #pragma unroll
            for (int r = 0; r < 4; ++r) g2[r] = sigmoidf_(gacc[r] + bi);
        }
        const ushortT* bpu = W2upT + ln * 32 + lq * 8;
        short8 bu = *(const short8*)bpu;
        #pragma unroll
        for (int c = 0; c < 2; ++c) {
            if (c == 1 && w >= 2) break;
            int mt = w + c * 4;
            const ushortT* ap = vhid2A + (mt * 16 + ln) * 24 + lq * 8;
            short8 a = {0, 0, 0, 0, 0, 0, 0, 0};
            if (lq < 2) a = *(const short8*)ap;
            f32x4 acc = {0,0,0,0};
            acc = MFMA(a, bu, acc);
            #pragma unroll
            for (int r = 0; r < 4; ++r) {
                int row = mt * 16 + lq * 4 + r;
                float vfin = b2f(v1A[row * 24 + ln]) + acc[r] * g2[r];
                v1A[row * 24 + ln] = f2b(vfin);
            }
        }
        // attention: sigmoid((s1+s2) . attW + b), 8 threads per edge
        {
            float sum = 0.f;
            int c0 = tj * 16;
            #pragma unroll
            for (int c = c0; c < c0 + 16; ++c)
                sum = fmaf(b2f(m2[te * 168 + c]) + b2f(s2s[te * 136 + c]), attW[c], sum);
            sum += __shfl_xor(sum, 4);
            sum += __shfl_xor(sum, 2);
            sum += __shfl_xor(sum, 1);
            if (tj == 0) attn[te] = sigmoidf_(sum + attb[0]);
        }
    }
    __syncthreads();   // (8)

    // ==== Phase L: scatter-add (8 threads per edge) ====
    {
        const int nr = is64 ? (int)pl[eg + te] : pi[eg + te];
        const int orow = nr * 176;
        const float at = attn[te];
        #pragma unroll
        for (int k = 0; k < 22; ++k) {
            int j = tj + k * 8;
            float val;
            if (j < 128) {
                val = (b2f(m2[te * 168 + j]) + b2f(s2s[te * 136 + j])) * at;
            } else {
                int r = j - 128, o = r / 3, sp = r - o * 3;
                val = b2f(v1A[(sp * 32 + te) * 24 + o]);
            }
            atomicAdd(&out[orow + j], val);
        }
    }
}

extern "C" void kernel_launch(void* const* d_in, const int* in_sizes, int n_in,
                              void* d_out, int out_size, void* d_ws, size_t ws_size,
                              hipStream_t stream) {
    const float* node_s = (const float*)d_in[0];
    const float* node_v = (const float*)d_in[1];
    const float* edge_s = (const float*)d_in[2];
    const float* edge_v = (const float*)d_in[3];
    const float* frames = (const float*)d_in[4];
    const float* W1d  = (const float*)d_in[5];
    const float* W1f  = (const float*)d_in[6];
    const float* W1so = (const float*)d_in[7];
    const float* b1so = (const float*)d_in[8];
    const float* W1up = (const float*)d_in[9];
    const float* W1g  = (const float*)d_in[10];
    const float* b1g  = (const float*)d_in[11];
    const float* W2d  = (const float*)d_in[12];
    const float* W2f  = (const float*)d_in[13];
    const float* W2so = (const float*)d_in[14];
    const float* b2so = (const float*)d_in[15];
    const float* W2up = (const float*)d_in[16];
    const float* W2g  = (const float*)d_in[17];
    const float* b2g  = (const float*)d_in[18];
    const float* attW = (const float*)d_in[19];
    const float* attb = (const float*)d_in[20];
    const void*  eidx = d_in[21];

    float* out = (float*)d_out;
    ushortT* ws16 = (ushortT*)d_ws;

    prep_kernel<<<294, 256, 0, stream>>>(W1so, W2so, W1d, W1f, W1g, W1up,
                                         W2d, W2f, W2g, W2up, ws16, out);

    edge_kernel<<<E_TOT / EPB, 256, 0, stream>>>(
        node_s, node_v, edge_s, edge_v, frames,
        b1so, b1g, b2so, b2g, attW, attb,
        (const ushortT*)ws16, eidx, out);
}

// Round 7
// 384.329 us; speedup vs baseline: 1.0672x; 1.0672x over previous
//
#include <hip/hip_runtime.h>
#include <hip/hip_bf16.h>

#define E_TOT 160000
#define NN    10000
#define EPB   32      // edges per block

typedef unsigned short ushortT;
typedef unsigned int   uintT;
typedef __attribute__((ext_vector_type(8))) short short8;
typedef __attribute__((ext_vector_type(4))) float f32x4;

__device__ __forceinline__ float sigmoidf_(float x) { return 1.0f / (1.0f + __expf(-x)); }
__device__ __forceinline__ float siluf_(float x) { return x * sigmoidf_(x); }

__device__ __forceinline__ ushortT f2b(float f) {
    union { float f; uintT u; } x; x.f = f;
    uintT r = x.u + 0x7fffu + ((x.u >> 16) & 1u);
    return (ushortT)(r >> 16);
}
__device__ __forceinline__ float b2f(ushortT h) {
    union { uintT u; float f; } x; x.u = ((uintT)h) << 16; return x.f;
}
__device__ __forceinline__ uintT pk2(float lo, float hi) {
    union { __hip_bfloat162 h; uintT u; } cv;
    cv.h = __float22bfloat162_rn(make_float2(lo, hi));
    return cv.u;
}
// 8 consecutive fp32 -> bf16 MFMA A-fragment
__device__ __forceinline__ short8 ldfrag(const float* p) {
    const float4 x = ((const float4*)p)[0];
    const float4 y = ((const float4*)p)[1];
    union { uintT u[4]; short8 s; } r;
    r.u[0] = pk2(x.x, x.y); r.u[1] = pk2(x.z, x.w);
    r.u[2] = pk2(y.x, y.y); r.u[3] = pk2(y.z, y.w);
    return r.s;
}

// ---- weight-table layout (ushort offsets within wt) ----
#define OFF_W1SO 0
#define OFF_W2SO 45056
#define OFF_W1DF 65536
#define OFF_W1G  68608
#define OFF_W1UP 70656
#define OFF_W2DF 71680
#define OFF_W2G  72704
#define OFF_W2UP 74752
// total 75264 ushorts = 150528 bytes

// ---- CSR workspace layout (bytes from ws base) ----
// FB   bf16[160000][176]  @0            (56,320,000)
// NOFF int[10001]         @56,320,000
// CUR  int[10000]         @56,360,016
// ELST int[160000]        @56,400,032
// WT   ushort[75264]      @57,040,032   -> need 57,190,560 total
#define FB_BYTES   56320000ULL
#define NOFF_OFF   56320000ULL
#define CUR_OFF    56360016ULL
#define ELST_OFF   56400032ULL
#define WT_OFF     57040032ULL
#define WS_NEED    57190560ULL

__global__ __launch_bounds__(256) void prep_kernel(
    const float* __restrict__ W1so, const float* __restrict__ W2so,
    const float* __restrict__ W1d,  const float* __restrict__ W1f,
    const float* __restrict__ W1g,  const float* __restrict__ W1up,
    const float* __restrict__ W2d,  const float* __restrict__ W2f,
    const float* __restrict__ W2g,  const float* __restrict__ W2up,
    ushortT* __restrict__ ws, float* __restrict__ out,
    int* __restrict__ cur, int csr)
{
    int i = blockIdx.x * 256 + threadIdx.x;    // grid 294*256 = 75264 exactly
    if (csr) {
        if (i < NN) cur[i] = 0;                // zero histogram counters
    } else {
        float4* o4 = (float4*)out;             // zero d_out: 440,000 float4
        #pragma unroll
        for (int k = 0; k < 6; ++k) {
            int z = i + k * 75264;
            if (z < 440000) o4[z] = make_float4(0.f, 0.f, 0.f, 0.f);
        }
    }
    if (i < OFF_W2SO) {                        // W1soT [n=128][k=352], k<333 real
        int n = i / 352, k = i - n * 352;
        ws[i] = (k < 333) ? f2b(W1so[k * 128 + n]) : (ushortT)0;
    } else if (i < OFF_W1DF) {                 // W2soT [128][160], k<153 real
        int j = i - OFF_W2SO, n = j / 160, k = j - n * 160;
        ws[i] = (k < 153) ? f2b(W2so[k * 128 + n]) : (ushortT)0;
    } else if (i < OFF_W1G) {                  // W1dfT [48][64]: n<36 Wd, 36..38 Wf
        int j = i - OFF_W1DF, n = j / 64, k = j - n * 64;
        float v = 0.f;
        if (k < 36) { if (n < 36) v = W1d[k * 36 + n]; else if (n < 39) v = W1f[k * 3 + (n - 36)]; }
        ws[i] = f2b(v);
    } else if (i < OFF_W1UP) {                 // W1gT [16][128]
        int j = i - OFF_W1G, n = j / 128, k = j - n * 128;
        ws[i] = f2b(W1g[k * 16 + n]);
    } else if (i < OFF_W2DF) {                 // W1upT [16][64], k<36 real
        int j = i - OFF_W1UP, n = j / 64, k = j - n * 64;
        ws[i] = (k < 36) ? f2b(W1up[k * 16 + n]) : (ushortT)0;
    } else if (i < OFF_W2G) {                  // W2dfT [32][32]: n<16 Wd, 16..18 Wf; k<16
        int j = i - OFF_W2DF, n = j / 32, k = j - n * 32;
        float v = 0.f;
        if (k < 16) { if (n < 16) v = W2d[k * 16 + n]; else if (n < 19) v = W2f[k * 3 + (n - 16)]; }
        ws[i] = f2b(v);
    } else if (i < OFF_W2UP) {                 // W2gT [16][128]
        int j = i - OFF_W2G, n = j / 128, k = j - n * 128;
        ws[i] = f2b(W2g[k * 16 + n]);
    } else {                                   // W2upT [16][32], k<16 real
        int j = i - OFF_W2UP, n = j / 32, k = j - n * 32;
        ws[i] = (k < 16) ? f2b(W2up[k * 16 + n]) : (ushortT)0;
    }
}

__device__ __forceinline__ bool idx_is64(const int* pi) {
    return (pi[1] | pi[3] | pi[5] | pi[7] | pi[9] | pi[11] | pi[13] | pi[15]) == 0;
}

__global__ __launch_bounds__(256) void hist_kernel(const void* __restrict__ eidx,
                                                   int* __restrict__ cur)
{
    int e = blockIdx.x * 256 + threadIdx.x;
    if (e >= E_TOT) return;
    const int* pi = (const int*)eidx;
    const long long* pl = (const long long*)eidx;
    int r = idx_is64(pi) ? (int)pl[e] : pi[e];
    atomicAdd(&cur[r], 1);
}

// single block: exclusive scan of cur[10000] -> noff[10001]; re-zero cur.
__global__ __launch_bounds__(256) void scan_kernel(int* __restrict__ cur,
                                                   int* __restrict__ noff)
{
    __shared__ int partial[256];
    const int t = threadIdx.x;
    const int base = t * 40;
    int loc[40];
    int s = 0;
    #pragma unroll
    for (int i = 0; i < 40; ++i) {
        int gi = base + i;
        int v = (gi < NN) ? cur[gi] : 0;
        loc[i] = v; s += v;
    }
    partial[t] = s;
    __syncthreads();
    for (int o = 1; o < 256; o <<= 1) {
        int v = (t >= o) ? partial[t - o] : 0;
        __syncthreads();
        partial[t] += v;
        __syncthreads();
    }
    int run = (t == 0) ? 0 : partial[t - 1];
    #pragma unroll
    for (int i = 0; i < 40; ++i) {
        int gi = base + i;
        if (gi < NN) { noff[gi] = run; run += loc[i]; cur[gi] = 0; }
    }
    if (t == 255) noff[NN] = partial[255];
}

__global__ __launch_bounds__(256) void fill_kernel(const void* __restrict__ eidx,
                                                   const int* __restrict__ noff,
                                                   int* __restrict__ cur,
                                                   int* __restrict__ elist)
{
    int e = blockIdx.x * 256 + threadIdx.x;
    if (e >= E_TOT) return;
    const int* pi = (const int*)eidx;
    const long long* pl = (const long long*)eidx;
    int r = idx_is64(pi) ? (int)pl[e] : pi[e];
    int pos = atomicAdd(&cur[r], 1);
    elist[noff[r] + pos] = e;
}

// one wave per node: gather FB rows of its edges, fp32 accumulate, coalesced out.
__global__ __launch_bounds__(256) void node_kernel(const ushortT* __restrict__ fb,
                                                   const int* __restrict__ noff,
                                                   const int* __restrict__ elist,
                                                   float* __restrict__ out)
{
    const int w = threadIdx.x >> 6, l = threadIdx.x & 63;
    const int n = blockIdx.x * 4 + w;          // grid 2500 -> 10000 nodes
    const int s = noff[n], eend = noff[n + 1];
    if (l < 44) {                               // 44 lanes x 4 bf16 cols = 176
        float a0 = 0.f, a1 = 0.f, a2 = 0.f, a3 = 0.f;
        for (int idx = s; idx < eend; ++idx) {
            int e = elist[idx];
            const uintT* p = (const uintT*)(fb + (size_t)e * 176 + l * 4);
            uintT d0 = p[0], d1 = p[1];
            a0 += b2f((ushortT)(d0 & 0xffff)); a1 += b2f((ushortT)(d0 >> 16));
            a2 += b2f((ushortT)(d1 & 0xffff)); a3 += b2f((ushortT)(d1 >> 16));
        }
        float4 st = make_float4(a0, a1, a2, a3);
        ((float4*)(out + (size_t)n * 176))[l] = st;
    }
}

#define MFMA(a, b, c) __builtin_amdgcn_mfma_f32_16x16x32_bf16((a), (b), (c), 0, 0, 0)

// LDS 31,104 B -> 5 blocks/CU. 8 barriers. Wave-local gates.
__global__ __launch_bounds__(256, 5) void edge_kernel(
    const float* __restrict__ node_s, const float* __restrict__ node_v,
    const float* __restrict__ edge_s, const float* __restrict__ edge_v,
    const float* __restrict__ frames,
    const float* __restrict__ b1so, const float* __restrict__ b1g,
    const float* __restrict__ b2so, const float* __restrict__ b2g,
    const float* __restrict__ attW, const float* __restrict__ attb,
    const ushortT* __restrict__ wsc,
    const void* __restrict__ eidx, float* __restrict__ out,
    ushortT* __restrict__ fb, int csr)
{
    const ushortT* W1T   = wsc + OFF_W1SO;
    const ushortT* W2T   = wsc + OFF_W2SO;
    const ushortT* W1dfT = wsc + OFF_W1DF;
    const ushortT* W1gT  = wsc + OFF_W1G;
    const ushortT* W1upT = wsc + OFF_W1UP;
    const ushortT* W2dfT = wsc + OFF_W2DF;
    const ushortT* W2gT  = wsc + OFF_W2G;
    const ushortT* W2upT = wsc + OFF_W2UP;

    __shared__ __align__(16) char smem[31104];
    ushortT* mvA     = (ushortT*)smem;                 // [96][40] (A->B) | m2 [32][168] (D->L)
    ushortT* m2      = (ushortT*)smem;
    ushortT* vhidA   = (ushortT*)(smem + 10752);       // [96][40] (B->E2) | s2s [32][136]
    ushortT* s2s     = (ushortT*)(smem + 10752);
    ushortT* normbuf = (ushortT*)(smem + 19456);       // [32][72] (A..C->D)
    ushortT* v1A     = (ushortT*)(smem + 19456);       // [96][24] (E->L)
    ushortT* vhid2A  = (ushortT*)(smem + 24064);       // [96][24] (G->J2/H)
    float*   vfr2f   = (float*)(smem + 28672);         // [96][3]  (G->H)
    float*   fr      = (float*)(smem + 29824);         // [32][9]
    float*   attn    = (float*)(smem + 30976);         // [32]

    const int t  = threadIdx.x;
    const int eg = blockIdx.x * EPB;
    const int w  = t >> 6, lane = t & 63, lq = lane >> 4, ln = lane & 15;
    const int te = t >> 3, tj = t & 7;     // 8 threads per edge
    const int p  = w & 1;

    const int* pi = (const int*)eidx;
    const long long* pl = (const long long*)eidx;
    const bool is64 = idx_is64(pi);

    // ==== Phase A: gathers (float4) + pads ====
    {
        const int nr = is64 ? (int)pl[eg + te] : pi[eg + te];
        const int nc = is64 ? (int)pl[E_TOT + eg + te] : pi[E_TOT + eg + te];
        const int nv4r = nr * 12, nv4c = nc * 12, ev4 = (eg + te) * 3;
        #pragma unroll
        for (int k = 0; k < 4; ++k) {           // 27 float4 per edge, 8 threads
            int q = tj + 8 * k;
            if (q < 27) {
                float4 v; int g0;
                if (q < 12)      { v = ((const float4*)node_v)[nv4r + q];        g0 = 4 * q; }
                else if (q < 15) { v = ((const float4*)edge_v)[ev4 + (q - 12)];  g0 = 48 + 4 * (q - 12); }
                else             { v = ((const float4*)node_v)[nv4c + (q - 15)]; g0 = 60 + 4 * (q - 15); }
                float vv[4] = {v.x, v.y, v.z, v.w};
                #pragma unroll
                for (int u = 0; u < 4; ++u) {
                    int g = g0 + u, c = g / 3, sp = g - c * 3;
                    mvA[(sp * 32 + te) * 40 + c] = f2b(vv[u]);
                }
            }
        }
        #pragma unroll
        for (int k = 0; k < 2; ++k) {           // frames: 9 per edge
            int j = tj + k * 8;
            if (j < 9) fr[te * 9 + j] = frames[(eg + te) * 9 + j];
        }
        #pragma unroll
        for (int k = 0; k < 3; ++k) {           // normbuf cols 45..63 = 0
            int c = 45 + tj + k * 8;
            if (c < 64) normbuf[te * 72 + c] = 0;
        }
        if (t < 192) {                          // mvA cols 36..39 = 0
            int r = t >> 1, cc = 36 + ((t & 1) << 1);
            *(uintT*)(mvA + r * 40 + cc) = 0;
        }
    }
    __syncthreads();   // (1)

    // ==== Phase B: mvA[96xK36] @ W1dfT[48][64] -> vhidA[96][<=40] ====
    for (int u = w; u < 18; u += 4) {
        int mt = u / 3, nt = u - mt * 3;
        const ushortT* ap = mvA + (mt * 16 + ln) * 40 + lq * 8;
        const ushortT* bp = W1dfT + (nt * 16 + ln) * 64 + lq * 8;
        f32x4 acc = {0.f, 0.f, 0.f, 0.f};
        acc = MFMA(*(const short8*)ap, *(const short8*)bp, acc);
        short8 a2 = {0, 0, 0, 0, 0, 0, 0, 0};
        if (lq == 0) a2 = *(const short8*)(ap + 32);
        acc = MFMA(a2, *(const short8*)(bp + 32), acc);
        if (nt < 2 || ln < 8) {
            ushortT* op = vhidA + (mt * 16 + lq * 4) * 40 + nt * 16 + ln;
            op[0]   = f2b(acc[0]); op[40]  = f2b(acc[1]);
            op[80]  = f2b(acc[2]); op[120] = f2b(acc[3]);
        }
    }
    __syncthreads();   // (2)

    // ==== Phase C: v_norm1 + local1 -> normbuf cols 0..44 ====
    {
        #pragma unroll
        for (int k = 0; k < 5; ++k) {
            int h = tj + k * 8;
            if (h < 36) {
                float a0 = b2f(vhidA[te * 40 + h]);
                float a1 = b2f(vhidA[(32 + te) * 40 + h]);
                float a2 = b2f(vhidA[(64 + te) * 40 + h]);
                normbuf[te * 72 + h] = f2b(sqrtf(fmaf(a0, a0, fmaf(a1, a1, fmaf(a2, a2, 1e-8f)))));
            }
        }
        for (int i = t; i < 288; i += 256) {
            int e = i / 9, r = i - e * 9, a = r / 3, b = r - a * 3;
            float x = fr[e * 9 + b * 3 + 0] * b2f(vhidA[e * 40 + 36 + a])
                    + fr[e * 9 + b * 3 + 1] * b2f(vhidA[(32 + e) * 40 + 36 + a])
                    + fr[e * 9 + b * 3 + 2] * b2f(vhidA[(64 + e) * 40 + 36 + a]);
            normbuf[e * 72 + 36 + r] = f2b(x);
        }
    }
    __syncthreads();   // (3)

    // ==== Phase D: s_out1 — A direct from global (k<288) + normbuf (k 288..351) ====
    {
        const int klq = lq * 8;
        const int e0 = ln, e1 = 16 + ln;
        int r0, c0, r1, c1;
        if (is64) {
            r0 = (int)pl[eg + e0]; r1 = (int)pl[eg + e1];
            c0 = (int)pl[E_TOT + eg + e0]; c1 = (int)pl[E_TOT + eg + e1];
        } else {
            r0 = pi[eg + e0]; r1 = pi[eg + e1];
            c0 = pi[E_TOT + eg + e0]; c1 = pi[E_TOT + eg + e1];
        }
        r0 *= 128; c0 *= 128; r1 *= 128; c1 *= 128;
        const int eb0 = (eg + e0) * 32, eb1 = (eg + e1) * 32;
        f32x4 acc00 = {0,0,0,0}, acc01 = {0,0,0,0}, acc10 = {0,0,0,0}, acc11 = {0,0,0,0};
        const ushortT* b0p = W1T + (w * 32 + ln) * 352 + klq;
        const ushortT* b1p = W1T + (w * 32 + 16 + ln) * 352 + klq;
        #pragma unroll
        for (int ks = 0; ks < 9; ++ks) {
            const float *pa0, *pa1;
            if (ks < 4)       { pa0 = node_s + r0 + ks * 32 + klq;        pa1 = node_s + r1 + ks * 32 + klq; }
            else if (ks == 4) { pa0 = edge_s + eb0 + klq;                 pa1 = edge_s + eb1 + klq; }
            else              { pa0 = node_s + c0 + (ks - 5) * 32 + klq;  pa1 = node_s + c1 + (ks - 5) * 32 + klq; }
            short8 a0 = ldfrag(pa0);
            short8 a1 = ldfrag(pa1);
            short8 b0 = *(const short8*)(b0p + ks * 32);
            short8 b1 = *(const short8*)(b1p + ks * 32);
            acc00 = MFMA(a0, b0, acc00); acc01 = MFMA(a0, b1, acc01);
            acc10 = MFMA(a1, b0, acc10); acc11 = MFMA(a1, b1, acc11);
        }
        #pragma unroll
        for (int ks = 9; ks < 11; ++ks) {
            short8 a0 = *(const short8*)(normbuf + e0 * 72 + (ks - 9) * 32 + klq);
            short8 a1 = *(const short8*)(normbuf + e1 * 72 + (ks - 9) * 32 + klq);
            short8 b0 = *(const short8*)(b0p + ks * 32);
            short8 b1 = *(const short8*)(b1p + ks * 32);
            acc00 = MFMA(a0, b0, acc00); acc01 = MFMA(a0, b1, acc01);
            acc10 = MFMA(a1, b0, acc10); acc11 = MFMA(a1, b1, acc11);
        }
        const int n0 = w * 32 + ln, n1 = n0 + 16;
        float bi0 = b1so[n0], bi1 = b1so[n1];
        #pragma unroll
        for (int r = 0; r < 4; ++r) {
            int m0 = lq * 4 + r;
            m2[m0 * 168 + n0]        = f2b(siluf_(acc00[r] + bi0));
            m2[m0 * 168 + n1]        = f2b(siluf_(acc01[r] + bi1));
            m2[(16 + m0) * 168 + n0] = f2b(siluf_(acc10[r] + bi0));
            m2[(16 + m0) * 168 + n1] = f2b(siluf_(acc11[r] + bi1));
        }
    }
    __syncthreads();   // (4)

    // ==== Phase E+G (wave-local) ====
    {
        f32x4 gacc = {0,0,0,0};
        {
            const ushortT* ap = m2 + (p * 16 + ln) * 168;
            const ushortT* bp = W1gT + ln * 128;
            #pragma unroll
            for (int ks = 0; ks < 4; ++ks)
                gacc = MFMA(*(const short8*)(ap + ks * 32 + lq * 8),
                            *(const short8*)(bp + ks * 32 + lq * 8), gacc);
        }
        float g1[4];
        {
            float bi = b1g[ln];
            #pragma unroll
            for (int r = 0; r < 4; ++r) g1[r] = sigmoidf_(gacc[r] + bi);
        }
        const ushortT* bpu = W1upT + ln * 64 + lq * 8;
        short8 bu1 = *(const short8*)bpu;
        short8 bu2 = *(const short8*)(bpu + 32);
        #pragma unroll
        for (int c = 0; c < 2; ++c) {
            if (c == 1 && w >= 2) break;
            int mt = w + c * 4;
            const ushortT* ap = vhidA + (mt * 16 + ln) * 40 + lq * 8;
            f32x4 acc = {0,0,0,0};
            acc = MFMA(*(const short8*)ap, bu1, acc);
            short8 a2 = {0, 0, 0, 0, 0, 0, 0, 0};
            if (lq == 0) a2 = *(const short8*)(ap + 32);
            acc = MFMA(a2, bu2, acc);
            #pragma unroll
            for (int r = 0; r < 4; ++r) {
                int row = mt * 16 + lq * 4 + r;
                v1A[row * 24 + ln] = f2b(acc[r] * g1[r]);
            }
        }
        #pragma unroll
        for (int c = 0; c < 2; ++c) {
            if (c == 1 && w >= 2) break;
            int mt = w + c * 4;
            const ushortT* ap = v1A + (mt * 16 + ln) * 24 + lq * 8;
            short8 a = {0, 0, 0, 0, 0, 0, 0, 0};
            if (lq < 2) a = *(const short8*)ap;
            #pragma unroll
            for (int nt = 0; nt < 2; ++nt) {
                const ushortT* bp = W2dfT + (nt * 16 + ln) * 32 + lq * 8;
                f32x4 acc = {0,0,0,0};
                acc = MFMA(a, *(const short8*)bp, acc);
                if (nt == 0) {
                    ushortT* op = vhid2A + (mt * 16 + lq * 4) * 24 + ln;
                    op[0]  = f2b(acc[0]); op[24] = f2b(acc[1]);
                    op[48] = f2b(acc[2]); op[72] = f2b(acc[3]);
                } else if (ln < 3) {
                    float* op = vfr2f + (mt * 16 + lq * 4) * 3 + ln;
                    op[0] = acc[0]; op[3] = acc[1]; op[6] = acc[2]; op[9] = acc[3];
                }
            }
        }
    }
    __syncthreads();   // (5)

    // ==== Phase H: norm2 + local2 + zero pad into m2 cols 128..159 ====
    {
        #pragma unroll
        for (int k = 0; k < 2; ++k) {
            int i = t + k * 256, e = i >> 4, h = i & 15;
            float a0 = b2f(vhid2A[e * 24 + h]);
            float a1 = b2f(vhid2A[(32 + e) * 24 + h]);
            float a2 = b2f(vhid2A[(64 + e) * 24 + h]);
            m2[e * 168 + 128 + h] = f2b(sqrtf(fmaf(a0, a0, fmaf(a1, a1, fmaf(a2, a2, 1e-8f)))));
        }
        for (int i = t; i < 288; i += 256) {
            int e = i / 9, r = i - e * 9, a = r / 3, b = r - a * 3;
            float x = fr[e * 9 + b * 3 + 0] * vfr2f[e * 3 + a]
                    + fr[e * 9 + b * 3 + 1] * vfr2f[(32 + e) * 3 + a]
                    + fr[e * 9 + b * 3 + 2] * vfr2f[(64 + e) * 3 + a];
            m2[e * 168 + 144 + r] = f2b(x);
        }
        if (tj) m2[te * 168 + 152 + tj] = 0;
    }
    __syncthreads();   // (6)

    // ==== Phase I: s_out2 = m2[32][160] @ W2soT -> s2s (silu) ====
    {
        f32x4 acc00 = {0,0,0,0}, acc01 = {0,0,0,0}, acc10 = {0,0,0,0}, acc11 = {0,0,0,0};
        const ushortT* a0p = m2 + ln * 168 + lq * 8;
        const ushortT* a1p = m2 + (16 + ln) * 168 + lq * 8;
        const ushortT* b0p = W2T + (w * 32 + ln) * 160 + lq * 8;
        const ushortT* b1p = W2T + (w * 32 + 16 + ln) * 160 + lq * 8;
        #pragma unroll
        for (int ks = 0; ks < 5; ++ks) {
            short8 a0 = *(const short8*)(a0p + ks * 32);
            short8 a1 = *(const short8*)(a1p + ks * 32);
            short8 b0 = *(const short8*)(b0p + ks * 32);
            short8 b1 = *(const short8*)(b1p + ks * 32);
            acc00 = MFMA(a0, b0, acc00); acc01 = MFMA(a0, b1, acc01);
            acc10 = MFMA(a1, b0, acc10); acc11 = MFMA(a1, b1, acc11);
        }
        const int n0 = w * 32 + ln, n1 = n0 + 16;
        float bi0 = b2so[n0], bi1 = b2so[n1];
        #pragma unroll
        for (int r = 0; r < 4; ++r) {
            int m0 = lq * 4 + r;
            s2s[m0 * 136 + n0]        = f2b(siluf_(acc00[r] + bi0));
            s2s[m0 * 136 + n1]        = f2b(siluf_(acc01[r] + bi1));
            s2s[(16 + m0) * 136 + n0] = f2b(siluf_(acc10[r] + bi0));
            s2s[(16 + m0) * 136 + n1] = f2b(siluf_(acc11[r] + bi1));
        }
    }
    __syncthreads();   // (7)

    // ==== Phase J (wave-local) + attention ====
    {
        f32x4 gacc = {0,0,0,0};
        {
            const ushortT* ap = s2s + (p * 16 + ln) * 136;
            const ushortT* bp = W2gT + ln * 128;
            #pragma unroll
            for (int ks = 0; ks < 4; ++ks)
                gacc = MFMA(*(const short8*)(ap + ks * 32 + lq * 8),
                            *(const short8*)(bp + ks * 32 + lq * 8), gacc);
        }
        float g2[4];
        {
            float bi = b2g[ln];
            #pragma unroll
            for (int r = 0; r < 4; ++r) g2[r] = sigmoidf_(gacc[r] + bi);
        }
        const ushortT* bpu = W2upT + ln * 32 + lq * 8;
        short8 bu = *(const short8*)bpu;
        #pragma unroll
        for (int c = 0; c < 2; ++c) {
            if (c == 1 && w >= 2) break;
            int mt = w + c * 4;
            const ushortT* ap = vhid2A + (mt * 16 + ln) * 24 + lq * 8;
            short8 a = {0, 0, 0, 0, 0, 0, 0, 0};
            if (lq < 2) a = *(const short8*)ap;
            f32x4 acc = {0,0,0,0};
            acc = MFMA(a, bu, acc);
            #pragma unroll
            for (int r = 0; r < 4; ++r) {
                int row = mt * 16 + lq * 4 + r;
                float vfin = b2f(v1A[row * 24 + ln]) + acc[r] * g2[r];
                v1A[row * 24 + ln] = f2b(vfin);
            }
        }
        {
            float sum = 0.f;
            int c0 = tj * 16;
            #pragma unroll
            for (int c = c0; c < c0 + 16; ++c)
                sum = fmaf(b2f(m2[te * 168 + c]) + b2f(s2s[te * 136 + c]), attW[c], sum);
            sum += __shfl_xor(sum, 4);
            sum += __shfl_xor(sum, 2);
            sum += __shfl_xor(sum, 1);
            if (tj == 0) attn[te] = sigmoidf_(sum + attb[0]);
        }
    }
    __syncthreads();   // (8)

    // ==== Phase L: per-edge output ====
    {
        const float at = attn[te];
        if (csr) {
            ushortT* fbe = fb + (size_t)(eg + te) * 176;
            #pragma unroll
            for (int k = 0; k < 11; ++k) {
                int j = 2 * tj + 16 * k;
                float v0, v1;
                if (j < 128) {
                    v0 = (b2f(m2[te * 168 + j])     + b2f(s2s[te * 136 + j]))     * at;
                    v1 = (b2f(m2[te * 168 + j + 1]) + b2f(s2s[te * 136 + j + 1])) * at;
                } else {
                    int r = j - 128;
                    int o0 = r / 3,        sp0 = r - o0 * 3;
                    int o1 = (r + 1) / 3,  sp1 = (r + 1) - o1 * 3;
                    v0 = b2f(v1A[(sp0 * 32 + te) * 24 + o0]);
                    v1 = b2f(v1A[(sp1 * 32 + te) * 24 + o1]);
                }
                *(uintT*)(fbe + j) = pk2(v0, v1);
            }
        } else {
            const int nr = is64 ? (int)pl[eg + te] : pi[eg + te];
            const int orow = nr * 176;
            #pragma unroll
            for (int k = 0; k < 22; ++k) {
                int j = tj + k * 8;
                float val;
                if (j < 128) {
                    val = (b2f(m2[te * 168 + j]) + b2f(s2s[te * 136 + j])) * at;
                } else {
                    int r = j - 128, o = r / 3, sp = r - o * 3;
                    val = b2f(v1A[(sp * 32 + te) * 24 + o]);
                }
                atomicAdd(&out[orow + j], val);
            }
        }
    }
}

extern "C" void kernel_launch(void* const* d_in, const int* in_sizes, int n_in,
                              void* d_out, int out_size, void* d_ws, size_t ws_size,
                              hipStream_t stream) {
    const float* node_s = (const float*)d_in[0];
    const float* node_v = (const float*)d_in[1];
    const float* edge_s = (const float*)d_in[2];
    const float* edge_v = (const float*)d_in[3];
    const float* frames = (const float*)d_in[4];
    const float* W1d  = (const float*)d_in[5];
    const float* W1f  = (const float*)d_in[6];
    const float* W1so = (const float*)d_in[7];
    const float* b1so = (const float*)d_in[8];
    const float* W1up = (const float*)d_in[9];
    const float* W1g  = (const float*)d_in[10];
    const float* b1g  = (const float*)d_in[11];
    const float* W2d  = (const float*)d_in[12];
    const float* W2f  = (const float*)d_in[13];
    const float* W2so = (const float*)d_in[14];
    const float* b2so = (const float*)d_in[15];
    const float* W2up = (const float*)d_in[16];
    const float* W2g  = (const float*)d_in[17];
    const float* b2g  = (const float*)d_in[18];
    const float* attW = (const float*)d_in[19];
    const float* attb = (const float*)d_in[20];
    const void*  eidx = d_in[21];

    float* out = (float*)d_out;
    char* ws = (char*)d_ws;

    const int csr = (ws_size >= WS_NEED) ? 1 : 0;
    ushortT* wt    = csr ? (ushortT*)(ws + WT_OFF)  : (ushortT*)ws;
    ushortT* fbuf  = csr ? (ushortT*)ws             : nullptr;
    int*     noff  = csr ? (int*)(ws + NOFF_OFF)    : nullptr;
    int*     cur   = csr ? (int*)(ws + CUR_OFF)     : nullptr;
    int*     elist = csr ? (int*)(ws + ELST_OFF)    : nullptr;

    prep_kernel<<<294, 256, 0, stream>>>(W1so, W2so, W1d, W1f, W1g, W1up,
                                         W2d, W2f, W2g, W2up, wt, out, cur, csr);

    if (csr) {
        hist_kernel<<<625, 256, 0, stream>>>(eidx, cur);
        scan_kernel<<<1, 256, 0, stream>>>(cur, noff);
        fill_kernel<<<625, 256, 0, stream>>>(eidx, noff, cur, elist);
    }

    edge_kernel<<<E_TOT / EPB, 256, 0, stream>>>(
        node_s, node_v, edge_s, edge_v, frames,
        b1so, b1g, b2so, b2g, attW, attb,
        (const ushortT*)wt, eidx, out, fbuf, csr);

    if (csr) {
        node_kernel<<<2500, 256, 0, stream>>>((const ushortT*)fbuf, noff, elist, out);
    }
}

// Round 8
// 333.152 us; speedup vs baseline: 1.2311x; 1.1536x over previous
//
#include <hip/hip_runtime.h>
#include <hip/hip_bf16.h>

#define E_TOT 160000
#define NN    10000
#define EPB   32      // edges per block

typedef unsigned short ushortT;
typedef unsigned int   uintT;
typedef __attribute__((ext_vector_type(8))) short short8;
typedef __attribute__((ext_vector_type(4))) float f32x4;

__device__ __forceinline__ float sigmoidf_(float x) { return 1.0f / (1.0f + __expf(-x)); }
__device__ __forceinline__ float siluf_(float x) { return x * sigmoidf_(x); }

__device__ __forceinline__ ushortT f2b(float f) {
    union { float f; uintT u; } x; x.f = f;
    uintT r = x.u + 0x7fffu + ((x.u >> 16) & 1u);
    return (ushortT)(r >> 16);
}
__device__ __forceinline__ float b2f(ushortT h) {
    union { uintT u; float f; } x; x.u = ((uintT)h) << 16; return x.f;
}
__device__ __forceinline__ uintT pk2(float lo, float hi) {
    union { __hip_bfloat162 h; uintT u; } cv;
    cv.h = __float22bfloat162_rn(make_float2(lo, hi));
    return cv.u;
}
// 8 consecutive fp32 -> bf16 MFMA A-fragment (fallback path)
__device__ __forceinline__ short8 ldfrag(const float* p) {
    const float4 x = ((const float4*)p)[0];
    const float4 y = ((const float4*)p)[1];
    union { uintT u[4]; short8 s; } r;
    r.u[0] = pk2(x.x, x.y); r.u[1] = pk2(x.z, x.w);
    r.u[2] = pk2(y.x, y.y); r.u[3] = pk2(y.z, y.w);
    return r.s;
}

// ---- weight-table layout (ushort offsets within wt) ----
#define OFF_W1SO 0
#define OFF_W2SO 45056
#define OFF_W1DF 65536
#define OFF_W1G  68608
#define OFF_W1UP 70656
#define OFF_W2DF 71680
#define OFF_W2G  72704
#define OFF_W2UP 74752
// total 75264 ushorts = 150528 bytes

// ---- CSR workspace layout (bytes from ws base) ----
#define NOFF_OFF   56320000ULL
#define CUR_OFF    56360016ULL
#define EPOS_OFF   56400032ULL
#define WT_OFF     57040032ULL
#define WS_CSR     57190560ULL              // FB+NOFF+CUR+EPOS+WT
#define NS16_OFF   57190560ULL              // bf16 node_s [10000][128]
#define WS_NS      59750560ULL
#define ES16_OFF   59750560ULL              // bf16 edge_s [160000][32]
#define WS_ES      69990560ULL

__global__ __launch_bounds__(256) void prep_kernel(
    const float* __restrict__ W1so, const float* __restrict__ W2so,
    const float* __restrict__ W1d,  const float* __restrict__ W1f,
    const float* __restrict__ W1g,  const float* __restrict__ W1up,
    const float* __restrict__ W2d,  const float* __restrict__ W2f,
    const float* __restrict__ W2g,  const float* __restrict__ W2up,
    ushortT* __restrict__ ws, float* __restrict__ out,
    int* __restrict__ cur, int csr)
{
    int i = blockIdx.x * 256 + threadIdx.x;    // grid 294*256 = 75264 exactly
    if (csr) {
        if (i < NN) cur[i] = 0;
    } else {
        float4* o4 = (float4*)out;             // zero d_out: 440,000 float4
        #pragma unroll
        for (int k = 0; k < 6; ++k) {
            int z = i + k * 75264;
            if (z < 440000) o4[z] = make_float4(0.f, 0.f, 0.f, 0.f);
        }
    }
    if (i < OFF_W2SO) {                        // W1soT [n=128][k=352], k<333 real
        int n = i / 352, k = i - n * 352;
        ws[i] = (k < 333) ? f2b(W1so[k * 128 + n]) : (ushortT)0;
    } else if (i < OFF_W1DF) {                 // W2soT [128][160], k<153 real
        int j = i - OFF_W2SO, n = j / 160, k = j - n * 160;
        ws[i] = (k < 153) ? f2b(W2so[k * 128 + n]) : (ushortT)0;
    } else if (i < OFF_W1G) {                  // W1dfT [48][64]: n<36 Wd, 36..38 Wf
        int j = i - OFF_W1DF, n = j / 64, k = j - n * 64;
        float v = 0.f;
        if (k < 36) { if (n < 36) v = W1d[k * 36 + n]; else if (n < 39) v = W1f[k * 3 + (n - 36)]; }
        ws[i] = f2b(v);
    } else if (i < OFF_W1UP) {                 // W1gT [16][128]
        int j = i - OFF_W1G, n = j / 128, k = j - n * 128;
        ws[i] = f2b(W1g[k * 16 + n]);
    } else if (i < OFF_W2DF) {                 // W1upT [16][64], k<36 real
        int j = i - OFF_W1UP, n = j / 64, k = j - n * 64;
        ws[i] = (k < 36) ? f2b(W1up[k * 16 + n]) : (ushortT)0;
    } else if (i < OFF_W2G) {                  // W2dfT [32][32]: n<16 Wd, 16..18 Wf; k<16
        int j = i - OFF_W2DF, n = j / 32, k = j - n * 32;
        float v = 0.f;
        if (k < 16) { if (n < 16) v = W2d[k * 16 + n]; else if (n < 19) v = W2f[k * 3 + (n - 16)]; }
        ws[i] = f2b(v);
    } else if (i < OFF_W2UP) {                 // W2gT [16][128]
        int j = i - OFF_W2G, n = j / 128, k = j - n * 128;
        ws[i] = f2b(W2g[k * 16 + n]);
    } else {                                   // W2upT [16][32], k<16 real
        int j = i - OFF_W2UP, n = j / 32, k = j - n * 32;
        ws[i] = (k < 16) ? f2b(W2up[k * 16 + n]) : (ushortT)0;
    }
}

__device__ __forceinline__ bool idx_is64(const int* pi) {
    return (pi[1] | pi[3] | pi[5] | pi[7] | pi[9] | pi[11] | pi[13] | pi[15]) == 0;
}

// histogram + (optional) bf16 pre-conversion of node_s / edge_s
__global__ __launch_bounds__(256) void hist_kernel(const void* __restrict__ eidx,
                                                   int* __restrict__ cur,
                                                   const float* __restrict__ node_s,
                                                   const float* __restrict__ edge_s,
                                                   ushortT* __restrict__ ns16,
                                                   ushortT* __restrict__ es16)
{
    int i = blockIdx.x * 256 + threadIdx.x;    // grid 625*256 = 160000 exactly
    const int* pi = (const int*)eidx;
    const long long* pl = (const long long*)eidx;
    int r = idx_is64(pi) ? (int)pl[i] : pi[i];
    atomicAdd(&cur[r], 1);
    if (ns16) {                                 // 1,280,000 elems, 8/thread
        float4 x = ((const float4*)node_s)[i * 2];
        float4 y = ((const float4*)node_s)[i * 2 + 1];
        uint4 st;
        st.x = pk2(x.x, x.y); st.y = pk2(x.z, x.w);
        st.z = pk2(y.x, y.y); st.w = pk2(y.z, y.w);
        ((uint4*)ns16)[i] = st;
    }
    if (es16) {                                 // 5,120,000 elems, 32/thread
        #pragma unroll
        for (int k = 0; k < 4; ++k) {
            float4 x = ((const float4*)edge_s)[i * 8 + 2 * k];
            float4 y = ((const float4*)edge_s)[i * 8 + 2 * k + 1];
            uint4 st;
            st.x = pk2(x.x, x.y); st.y = pk2(x.z, x.w);
            st.z = pk2(y.x, y.y); st.w = pk2(y.z, y.w);
            ((uint4*)es16)[i * 4 + k] = st;
        }
    }
}

// single block: exclusive scan of cur[10000] -> noff[10001]; re-zero cur.
__global__ __launch_bounds__(256) void scan_kernel(int* __restrict__ cur,
                                                   int* __restrict__ noff)
{
    __shared__ int partial[256];
    const int t = threadIdx.x;
    const int base = t * 40;
    int loc[40];
    int s = 0;
    #pragma unroll
    for (int i = 0; i < 40; ++i) {
        int gi = base + i;
        int v = (gi < NN) ? cur[gi] : 0;
        loc[i] = v; s += v;
    }
    partial[t] = s;
    __syncthreads();
    for (int o = 1; o < 256; o <<= 1) {
        int v = (t >= o) ? partial[t - o] : 0;
        __syncthreads();
        partial[t] += v;
        __syncthreads();
    }
    int run = (t == 0) ? 0 : partial[t - 1];
    #pragma unroll
    for (int i = 0; i < 40; ++i) {
        int gi = base + i;
        if (gi < NN) { noff[gi] = run; run += loc[i]; cur[gi] = 0; }
    }
    if (t == 255) noff[NN] = partial[255];
}

// epos[e] = compacted CSR slot of edge e
__global__ __launch_bounds__(256) void fill_kernel(const void* __restrict__ eidx,
                                                   const int* __restrict__ noff,
                                                   int* __restrict__ cur,
                                                   int* __restrict__ epos)
{
    int e = blockIdx.x * 256 + threadIdx.x;
    if (e >= E_TOT) return;
    const int* pi = (const int*)eidx;
    const long long* pl = (const long long*)eidx;
    int r = idx_is64(pi) ? (int)pl[e] : pi[e];
    int pos = atomicAdd(&cur[r], 1);
    epos[e] = noff[r] + pos;
}

// one wave per node: FB rows are CSR-contiguous -> pure streaming read.
__global__ __launch_bounds__(256) void node_kernel(const ushortT* __restrict__ fb,
                                                   const int* __restrict__ noff,
                                                   float* __restrict__ out)
{
    const int w = threadIdx.x >> 6, l = threadIdx.x & 63;
    const int n = blockIdx.x * 4 + w;          // grid 2500 -> 10000 nodes
    if (l >= 44) return;                        // 44 lanes x 4 bf16 cols = 176 (no barriers below)
    const int s = noff[n], eend = noff[n + 1];
    float a0 = 0.f, a1 = 0.f, a2 = 0.f, a3 = 0.f;
    int idx = s;
    for (; idx + 2 <= eend; idx += 2) {
        uint2 p0 = *(const uint2*)(fb + (size_t)idx * 176 + l * 4);
        uint2 p1 = *(const uint2*)(fb + (size_t)(idx + 1) * 176 + l * 4);
        a0 += b2f((ushortT)(p0.x & 0xffff)); a1 += b2f((ushortT)(p0.x >> 16));
        a2 += b2f((ushortT)(p0.y & 0xffff)); a3 += b2f((ushortT)(p0.y >> 16));
        a0 += b2f((ushortT)(p1.x & 0xffff)); a1 += b2f((ushortT)(p1.x >> 16));
        a2 += b2f((ushortT)(p1.y & 0xffff)); a3 += b2f((ushortT)(p1.y >> 16));
    }
    if (idx < eend) {
        uint2 p0 = *(const uint2*)(fb + (size_t)idx * 176 + l * 4);
        a0 += b2f((ushortT)(p0.x & 0xffff)); a1 += b2f((ushortT)(p0.x >> 16));
        a2 += b2f((ushortT)(p0.y & 0xffff)); a3 += b2f((ushortT)(p0.y >> 16));
    }
    ((float4*)(out + (size_t)n * 176))[l] = make_float4(a0, a1, a2, a3);
}

#define MFMA(a, b, c) __builtin_amdgcn_mfma_f32_16x16x32_bf16((a), (b), (c), 0, 0, 0)

// LDS 31,104 B -> 5 blocks/CU. 8 barriers. Wave-local gates.
__global__ __launch_bounds__(256, 5) void edge_kernel(
    const float* __restrict__ node_s, const float* __restrict__ node_v,
    const float* __restrict__ edge_s, const float* __restrict__ edge_v,
    const float* __restrict__ frames,
    const float* __restrict__ b1so, const float* __restrict__ b1g,
    const float* __restrict__ b2so, const float* __restrict__ b2g,
    const float* __restrict__ attW, const float* __restrict__ attb,
    const ushortT* __restrict__ wsc,
    const void* __restrict__ eidx, float* __restrict__ out,
    ushortT* __restrict__ fb, const int* __restrict__ epos,
    const ushortT* __restrict__ ns16, const ushortT* __restrict__ es16,
    int csr)
{
    const ushortT* W1T   = wsc + OFF_W1SO;
    const ushortT* W2T   = wsc + OFF_W2SO;
    const ushortT* W1dfT = wsc + OFF_W1DF;
    const ushortT* W1gT  = wsc + OFF_W1G;
    const ushortT* W1upT = wsc + OFF_W1UP;
    const ushortT* W2dfT = wsc + OFF_W2DF;
    const ushortT* W2gT  = wsc + OFF_W2G;
    const ushortT* W2upT = wsc + OFF_W2UP;

    __shared__ __align__(16) char smem[31104];
    ushortT* mvA     = (ushortT*)smem;                 // [96][40] (A->B) | m2 [32][168] (D->L)
    ushortT* m2      = (ushortT*)smem;
    ushortT* vhidA   = (ushortT*)(smem + 10752);       // [96][40] (B->E2) | s2s [32][136]
    ushortT* s2s     = (ushortT*)(smem + 10752);
    ushortT* normbuf = (ushortT*)(smem + 19456);       // [32][72] (A..C->D)
    ushortT* v1A     = (ushortT*)(smem + 19456);       // [96][24] (E->L)
    ushortT* vhid2A  = (ushortT*)(smem + 24064);       // [96][24] (G->J2/H)
    float*   vfr2f   = (float*)(smem + 28672);         // [96][3]  (G->H)
    float*   fr      = (float*)(smem + 29824);         // [32][9]
    float*   attn    = (float*)(smem + 30976);         // [32]

    const int t  = threadIdx.x;
    const int eg = blockIdx.x * EPB;
    const int w  = t >> 6, lane = t & 63, lq = lane >> 4, ln = lane & 15;
    const int te = t >> 3, tj = t & 7;     // 8 threads per edge
    const int p  = w & 1;

    const int* pi = (const int*)eidx;
    const long long* pl = (const long long*)eidx;
    const bool is64 = idx_is64(pi);

    // ==== Phase A: gathers (12-elem chunks: 3 float4 -> 6 packed uint) ====
    {
        const int nr = is64 ? (int)pl[eg + te] : pi[eg + te];
        const int nc = is64 ? (int)pl[E_TOT + eg + te] : pi[E_TOT + eg + te];
        #pragma unroll
        for (int mi = 0; mi < 2; ++mi) {
            if (mi == 1 && tj != 0) break;
            int m = (mi == 0) ? tj : 8;        // chunks 0..8; chunk = 4 c-cols x 3 sp
            const float* src;
            if (m < 4)       src = node_v + nr * 48 + 12 * m;
            else if (m == 4) src = edge_v + (eg + te) * 12;
            else             src = node_v + nc * 48 + 12 * (m - 5);
            float4 x = ((const float4*)src)[0];
            float4 y = ((const float4*)src)[1];
            float4 z = ((const float4*)src)[2];
            float v[12] = {x.x, x.y, x.z, x.w, y.x, y.y, y.z, y.w, z.x, z.y, z.z, z.w};
            int c0 = 4 * m;
            #pragma unroll
            for (int sp = 0; sp < 3; ++sp) {
                *(uintT*)(mvA + (sp * 32 + te) * 40 + c0)     = pk2(v[sp],     v[3 + sp]);
                *(uintT*)(mvA + (sp * 32 + te) * 40 + c0 + 2) = pk2(v[6 + sp], v[9 + sp]);
            }
        }
        #pragma unroll
        for (int k = 0; k < 2; ++k) {           // frames: 9 per edge
            int j = tj + k * 8;
            if (j < 9) fr[te * 9 + j] = frames[(eg + te) * 9 + j];
        }
        #pragma unroll
        for (int k = 0; k < 3; ++k) {           // normbuf cols 45..63 = 0
            int c = 45 + tj + k * 8;
            if (c < 64) normbuf[te * 72 + c] = 0;
        }
        if (t < 192) {                          // mvA cols 36..39 = 0
            int r = t >> 1, cc = 36 + ((t & 1) << 1);
            *(uintT*)(mvA + r * 40 + cc) = 0;
        }
    }
    __syncthreads();   // (1)

    // ==== Phase B: mvA[96xK36] @ W1dfT[48][64] -> vhidA[96][<=40] ====
    for (int u = w; u < 18; u += 4) {
        int mt = u / 3, nt = u - mt * 3;
        const ushortT* ap = mvA + (mt * 16 + ln) * 40 + lq * 8;
        const ushortT* bp = W1dfT + (nt * 16 + ln) * 64 + lq * 8;
        f32x4 acc = {0.f, 0.f, 0.f, 0.f};
        acc = MFMA(*(const short8*)ap, *(const short8*)bp, acc);
        short8 a2 = {0, 0, 0, 0, 0, 0, 0, 0};
        if (lq == 0) a2 = *(const short8*)(ap + 32);
        acc = MFMA(a2, *(const short8*)(bp + 32), acc);
        if (nt < 2 || ln < 8) {
            ushortT* op = vhidA + (mt * 16 + lq * 4) * 40 + nt * 16 + ln;
            op[0]   = f2b(acc[0]); op[40]  = f2b(acc[1]);
            op[80]  = f2b(acc[2]); op[120] = f2b(acc[3]);
        }
    }
    __syncthreads();   // (2)

    // ==== Phase C: v_norm1 + local1 -> normbuf cols 0..44 ====
    {
        #pragma unroll
        for (int k = 0; k < 5; ++k) {
            int h = tj + k * 8;
            if (h < 36) {
                float a0 = b2f(vhidA[te * 40 + h]);
                float a1 = b2f(vhidA[(32 + te) * 40 + h]);
                float a2 = b2f(vhidA[(64 + te) * 40 + h]);
                normbuf[te * 72 + h] = f2b(sqrtf(fmaf(a0, a0, fmaf(a1, a1, fmaf(a2, a2, 1e-8f)))));
            }
        }
        for (int i = t; i < 288; i += 256) {
            int e = i / 9, r = i - e * 9, a = r / 3, b = r - a * 3;
            float x = fr[e * 9 + b * 3 + 0] * b2f(vhidA[e * 40 + 36 + a])
                    + fr[e * 9 + b * 3 + 1] * b2f(vhidA[(32 + e) * 40 + 36 + a])
                    + fr[e * 9 + b * 3 + 2] * b2f(vhidA[(64 + e) * 40 + 36 + a]);
            normbuf[e * 72 + 36 + r] = f2b(x);
        }
    }
    __syncthreads();   // (3)

    // ==== Phase D: s_out1 — A from bf16 tables (or fp32 fallback) + normbuf ====
    {
        const int klq = lq * 8;
        const int e0 = ln, e1 = 16 + ln;
        int r0, c0, r1, c1;
        if (is64) {
            r0 = (int)pl[eg + e0]; r1 = (int)pl[eg + e1];
            c0 = (int)pl[E_TOT + eg + e0]; c1 = (int)pl[E_TOT + eg + e1];
        } else {
            r0 = pi[eg + e0]; r1 = pi[eg + e1];
            c0 = pi[E_TOT + eg + e0]; c1 = pi[E_TOT + eg + e1];
        }
        r0 *= 128; c0 *= 128; r1 *= 128; c1 *= 128;
        const int eb0 = (eg + e0) * 32, eb1 = (eg + e1) * 32;
        f32x4 acc00 = {0,0,0,0}, acc01 = {0,0,0,0}, acc10 = {0,0,0,0}, acc11 = {0,0,0,0};
        const ushortT* b0p = W1T + (w * 32 + ln) * 352 + klq;
        const ushortT* b1p = W1T + (w * 32 + 16 + ln) * 352 + klq;
        #pragma unroll
        for (int ks = 0; ks < 9; ++ks) {
            short8 a0, a1;
            if (ks < 4) {
                if (ns16) {
                    a0 = *(const short8*)(ns16 + r0 + ks * 32 + klq);
                    a1 = *(const short8*)(ns16 + r1 + ks * 32 + klq);
                } else {
                    a0 = ldfrag(node_s + r0 + ks * 32 + klq);
                    a1 = ldfrag(node_s + r1 + ks * 32 + klq);
                }
            } else if (ks == 4) {
                if (es16) {
                    a0 = *(const short8*)(es16 + eb0 + klq);
                    a1 = *(const short8*)(es16 + eb1 + klq);
                } else {
                    a0 = ldfrag(edge_s + eb0 + klq);
                    a1 = ldfrag(edge_s + eb1 + klq);
                }
            } else {
                if (ns16) {
                    a0 = *(const short8*)(ns16 + c0 + (ks - 5) * 32 + klq);
                    a1 = *(const short8*)(ns16 + c1 + (ks - 5) * 32 + klq);
                } else {
                    a0 = ldfrag(node_s + c0 + (ks - 5) * 32 + klq);
                    a1 = ldfrag(node_s + c1 + (ks - 5) * 32 + klq);
                }
            }
            short8 b0 = *(const short8*)(b0p + ks * 32);
            short8 b1 = *(const short8*)(b1p + ks * 32);
            acc00 = MFMA(a0, b0, acc00); acc01 = MFMA(a0, b1, acc01);
            acc10 = MFMA(a1, b0, acc10); acc11 = MFMA(a1, b1, acc11);
        }
        #pragma unroll
        for (int ks = 9; ks < 11; ++ks) {
            short8 a0 = *(const short8*)(normbuf + e0 * 72 + (ks - 9) * 32 + klq);
            short8 a1 = *(const short8*)(normbuf + e1 * 72 + (ks - 9) * 32 + klq);
            short8 b0 = *(const short8*)(b0p + ks * 32);
            short8 b1 = *(const short8*)(b1p + ks * 32);
            acc00 = MFMA(a0, b0, acc00); acc01 = MFMA(a0, b1, acc01);
            acc10 = MFMA(a1, b0, acc10); acc11 = MFMA(a1, b1, acc11);
        }
        const int n0 = w * 32 + ln, n1 = n0 + 16;
        float bi0 = b1so[n0], bi1 = b1so[n1];
        #pragma unroll
        for (int r = 0; r < 4; ++r) {
            int m0 = lq * 4 + r;
            m2[m0 * 168 + n0]        = f2b(siluf_(acc00[r] + bi0));
            m2[m0 * 168 + n1]        = f2b(siluf_(acc01[r] + bi1));
            m2[(16 + m0) * 168 + n0] = f2b(siluf_(acc10[r] + bi0));
            m2[(16 + m0) * 168 + n1] = f2b(siluf_(acc11[r] + bi1));
        }
    }
    __syncthreads();   // (4)

    // ==== Phase E+G (wave-local) ====
    {
        f32x4 gacc = {0,0,0,0};
        {
            const ushortT* ap = m2 + (p * 16 + ln) * 168;
            const ushortT* bp = W1gT + ln * 128;
            #pragma unroll
            for (int ks = 0; ks < 4; ++ks)
                gacc = MFMA(*(const short8*)(ap + ks * 32 + lq * 8),
                            *(const short8*)(bp + ks * 32 + lq * 8), gacc);
        }
        float g1[4];
        {
            float bi = b1g[ln];
            #pragma unroll
            for (int r = 0; r < 4; ++r) g1[r] = sigmoidf_(gacc[r] + bi);
        }
        const ushortT* bpu = W1upT + ln * 64 + lq * 8;
        short8 bu1 = *(const short8*)bpu;
        short8 bu2 = *(const short8*)(bpu + 32);
        #pragma unroll
        for (int c = 0; c < 2; ++c) {
            if (c == 1 && w >= 2) break;
            int mt = w + c * 4;
            const ushortT* ap = vhidA + (mt * 16 + ln) * 40 + lq * 8;
            f32x4 acc = {0,0,0,0};
            acc = MFMA(*(const short8*)ap, bu1, acc);
            short8 a2 = {0, 0, 0, 0, 0, 0, 0, 0};
            if (lq == 0) a2 = *(const short8*)(ap + 32);
            acc = MFMA(a2, bu2, acc);
            #pragma unroll
            for (int r = 0; r < 4; ++r) {
                int row = mt * 16 + lq * 4 + r;
                v1A[row * 24 + ln] = f2b(acc[r] * g1[r]);
            }
        }
        #pragma unroll
        for (int c = 0; c < 2; ++c) {
            if (c == 1 && w >= 2) break;
            int mt = w + c * 4;
            const ushortT* ap = v1A + (mt * 16 + ln) * 24 + lq * 8;
            short8 a = {0, 0, 0, 0, 0, 0, 0, 0};
            if (lq < 2) a = *(const short8*)ap;
            #pragma unroll
            for (int nt = 0; nt < 2; ++nt) {
                const ushortT* bp = W2dfT + (nt * 16 + ln) * 32 + lq * 8;
                f32x4 acc = {0,0,0,0};
                acc = MFMA(a, *(const short8*)bp, acc);
                if (nt == 0) {
                    ushortT* op = vhid2A + (mt * 16 + lq * 4) * 24 + ln;
                    op[0]  = f2b(acc[0]); op[24] = f2b(acc[1]);
                    op[48] = f2b(acc[2]); op[72] = f2b(acc[3]);
                } else if (ln < 3) {
                    float* op = vfr2f + (mt * 16 + lq * 4) * 3 + ln;
                    op[0] = acc[0]; op[3] = acc[1]; op[6] = acc[2]; op[9] = acc[3];
                }
            }
        }
    }
    __syncthreads();   // (5)

    // ==== Phase H: norm2 + local2 + zero pad into m2 cols 128..159 ====
    {
        #pragma unroll
        for (int k = 0; k < 2; ++k) {
            int i = t + k * 256, e = i >> 4, h = i & 15;
            float a0 = b2f(vhid2A[e * 24 + h]);
            float a1 = b2f(vhid2A[(32 + e) * 24 + h]);
            float a2 = b2f(vhid2A[(64 + e) * 24 + h]);
            m2[e * 168 + 128 + h] = f2b(sqrtf(fmaf(a0, a0, fmaf(a1, a1, fmaf(a2, a2, 1e-8f)))));
        }
        for (int i = t; i < 288; i += 256) {
            int e = i / 9, r = i - e * 9, a = r / 3, b = r - a * 3;
            float x = fr[e * 9 + b * 3 + 0] * vfr2f[e * 3 + a]
                    + fr[e * 9 + b * 3 + 1] * vfr2f[(32 + e) * 3 + a]
                    + fr[e * 9 + b * 3 + 2] * vfr2f[(64 + e) * 3 + a];
            m2[e * 168 + 144 + r] = f2b(x);
        }
        if (tj) m2[te * 168 + 152 + tj] = 0;
    }
    __syncthreads();   // (6)

    // ==== Phase I: s_out2 = m2[32][160] @ W2soT -> s2s (silu) ====
    {
        f32x4 acc00 = {0,0,0,0}, acc01 = {0,0,0,0}, acc10 = {0,0,0,0}, acc11 = {0,0,0,0};
        const ushortT* a0p = m2 + ln * 168 + lq * 8;
        const ushortT* a1p = m2 + (16 + ln) * 168 + lq * 8;
        const ushortT* b0p = W2T + (w * 32 + ln) * 160 + lq * 8;
        const ushortT* b1p = W2T + (w * 32 + 16 + ln) * 160 + lq * 8;
        #pragma unroll
        for (int ks = 0; ks < 5; ++ks) {
            short8 a0 = *(const short8*)(a0p + ks * 32);
            short8 a1 = *(const short8*)(a1p + ks * 32);
            short8 b0 = *(const short8*)(b0p + ks * 32);
            short8 b1 = *(const short8*)(b1p + ks * 32);
            acc00 = MFMA(a0, b0, acc00); acc01 = MFMA(a0, b1, acc01);
            acc10 = MFMA(a1, b0, acc10); acc11 = MFMA(a1, b1, acc11);
        }
        const int n0 = w * 32 + ln, n1 = n0 + 16;
        float bi0 = b2so[n0], bi1 = b2so[n1];
        #pragma unroll
        for (int r = 0; r < 4; ++r) {
            int m0 = lq * 4 + r;
            s2s[m0 * 136 + n0]        = f2b(siluf_(acc00[r] + bi0));
            s2s[m0 * 136 + n1]        = f2b(siluf_(acc01[r] + bi1));
            s2s[(16 + m0) * 136 + n0] = f2b(siluf_(acc10[r] + bi0));
            s2s[(16 + m0) * 136 + n1] = f2b(siluf_(acc11[r] + bi1));
        }
    }
    __syncthreads();   // (7)

    // ==== Phase J (wave-local) + attention ====
    {
        f32x4 gacc = {0,0,0,0};
        {
            const ushortT* ap = s2s + (p * 16 + ln) * 136;
            const ushortT* bp = W2gT + ln * 128;
            #pragma unroll
            for (int ks = 0; ks < 4; ++ks)
                gacc = MFMA(*(const short8*)(ap + ks * 32 + lq * 8),
                            *(const short8*)(bp + ks * 32 + lq * 8), gacc);
        }
        float g2[4];
        {
            float bi = b2g[ln];
            #pragma unroll
            for (int r = 0; r < 4; ++r) g2[r] = sigmoidf_(gacc[r] + bi);
        }
        const ushortT* bpu = W2upT + ln * 32 + lq * 8;
        short8 bu = *(const short8*)bpu;
        #pragma unroll
        for (int c = 0; c < 2; ++c) {
            if (c == 1 && w >= 2) break;
            int mt = w + c * 4;
            const ushortT* ap = vhid2A + (mt * 16 + ln) * 24 + lq * 8;
            short8 a = {0, 0, 0, 0, 0, 0, 0, 0};
            if (lq < 2) a = *(const short8*)ap;
            f32x4 acc = {0,0,0,0};
            acc = MFMA(a, bu, acc);
            #pragma unroll
            for (int r = 0; r < 4; ++r) {
                int row = mt * 16 + lq * 4 + r;
                float vfin = b2f(v1A[row * 24 + ln]) + acc[r] * g2[r];
                v1A[row * 24 + ln] = f2b(vfin);
            }
        }
        {
            float sum = 0.f;
            int c0 = tj * 16;
            #pragma unroll
            for (int c = c0; c < c0 + 16; ++c)
                sum = fmaf(b2f(m2[te * 168 + c]) + b2f(s2s[te * 136 + c]), attW[c], sum);
            sum += __shfl_xor(sum, 4);
            sum += __shfl_xor(sum, 2);
            sum += __shfl_xor(sum, 1);
            if (tj == 0) attn[te] = sigmoidf_(sum + attb[0]);
        }
    }
    __syncthreads();   // (8)

    // ==== Phase L: per-edge output ====
    {
        const float at = attn[te];
        if (csr) {
            const int pos = epos[eg + te];
            ushortT* fbe = fb + (size_t)pos * 176;
            #pragma unroll
            for (int k = 0; k < 11; ++k) {
                int j = 2 * tj + 16 * k;
                float v0, v1;
                if (j < 128) {
                    v0 = (b2f(m2[te * 168 + j])     + b2f(s2s[te * 136 + j]))     * at;
                    v1 = (b2f(m2[te * 168 + j + 1]) + b2f(s2s[te * 136 + j + 1])) * at;
                } else {
                    int r = j - 128;
                    int o0 = r / 3,        sp0 = r - o0 * 3;
                    int o1 = (r + 1) / 3,  sp1 = (r + 1) - o1 * 3;
                    v0 = b2f(v1A[(sp0 * 32 + te) * 24 + o0]);
                    v1 = b2f(v1A[(sp1 * 32 + te) * 24 + o1]);
                }
                *(uintT*)(fbe + j) = pk2(v0, v1);
            }
        } else {
            const int nr = is64 ? (int)pl[eg + te] : pi[eg + te];
            const int orow = nr * 176;
            #pragma unroll
            for (int k = 0; k < 22; ++k) {
                int j = tj + k * 8;
                float val;
                if (j < 128) {
                    val = (b2f(m2[te * 168 + j]) + b2f(s2s[te * 136 + j])) * at;
                } else {
                    int r = j - 128, o = r / 3, sp = r - o * 3;
                    val = b2f(v1A[(sp * 32 + te) * 24 + o]);
                }
                atomicAdd(&out[orow + j], val);
            }
        }
    }
}

extern "C" void kernel_launch(void* const* d_in, const int* in_sizes, int n_in,
                              void* d_out, int out_size, void* d_ws, size_t ws_size,
                              hipStream_t stream) {
    const float* node_s = (const float*)d_in[0];
    const float* node_v = (const float*)d_in[1];
    const float* edge_s = (const float*)d_in[2];
    const float* edge_v = (const float*)d_in[3];
    const float* frames = (const float*)d_in[4];
    const float* W1d  = (const float*)d_in[5];
    const float* W1f  = (const float*)d_in[6];
    const float* W1so = (const float*)d_in[7];
    const float* b1so = (const float*)d_in[8];
    const float* W1up = (const float*)d_in[9];
    const float* W1g  = (const float*)d_in[10];
    const float* b1g  = (const float*)d_in[11];
    const float* W2d  = (const float*)d_in[12];
    const float* W2f  = (const float*)d_in[13];
    const float* W2so = (const float*)d_in[14];
    const float* b2so = (const float*)d_in[15];
    const float* W2up = (const float*)d_in[16];
    const float* W2g  = (const float*)d_in[17];
    const float* b2g  = (const float*)d_in[18];
    const float* attW = (const float*)d_in[19];
    const float* attb = (const float*)d_in[20];
    const void*  eidx = d_in[21];

    float* out = (float*)d_out;
    char* ws = (char*)d_ws;

    int mode = 0;
    if (ws_size >= WS_ES)       mode = 3;
    else if (ws_size >= WS_NS)  mode = 2;
    else if (ws_size >= WS_CSR) mode = 1;
    const int csr = (mode >= 1);

    ushortT* wt    = csr ? (ushortT*)(ws + WT_OFF)  : (ushortT*)ws;
    ushortT* fbuf  = csr ? (ushortT*)ws             : nullptr;
    int*     noff  = csr ? (int*)(ws + NOFF_OFF)    : nullptr;
    int*     cur   = csr ? (int*)(ws + CUR_OFF)     : nullptr;
    int*     epos  = csr ? (int*)(ws + EPOS_OFF)    : nullptr;
    ushortT* ns16  = (mode >= 2) ? (ushortT*)(ws + NS16_OFF) : nullptr;
    ushortT* es16  = (mode >= 3) ? (ushortT*)(ws + ES16_OFF) : nullptr;

    prep_kernel<<<294, 256, 0, stream>>>(W1so, W2so, W1d, W1f, W1g, W1up,
                                         W2d, W2f, W2g, W2up, wt, out, cur, csr);

    if (csr) {
        hist_kernel<<<625, 256, 0, stream>>>(eidx, cur, node_s, edge_s, ns16, es16);
        scan_kernel<<<1, 256, 0, stream>>>(cur, noff);
        fill_kernel<<<625, 256, 0, stream>>>(eidx, noff, cur, epos);
    }

    edge_kernel<<<E_TOT / EPB, 256, 0, stream>>>(
        node_s, node_v, edge_s, edge_v, frames,
        b1so, b1g, b2so, b2g, attW, attb,
        (const ushortT*)wt, eidx, out, fbuf, epos, ns16, es16, csr);

    if (csr) {
        node_kernel<<<2500, 256, 0, stream>>>((const ushortT*)fbuf, noff, out);
    }
}

// Round 9
// 312.201 us; speedup vs baseline: 1.3137x; 1.0671x over previous
//
#include <hip/hip_runtime.h>
#include <hip/hip_bf16.h>

#define E_TOT 160000
#define NN    10000
#define EPB   32      // edges per block

typedef unsigned short ushortT;
typedef unsigned int   uintT;
typedef __attribute__((ext_vector_type(8))) short short8;
typedef __attribute__((ext_vector_type(4))) float f32x4;

__device__ __forceinline__ float sigmoidf_(float x) { return 1.0f / (1.0f + __expf(-x)); }
__device__ __forceinline__ float siluf_(float x) { return x * sigmoidf_(x); }

__device__ __forceinline__ ushortT f2b(float f) {
    union { float f; uintT u; } x; x.f = f;
    uintT r = x.u + 0x7fffu + ((x.u >> 16) & 1u);
    return (ushortT)(r >> 16);
}
__device__ __forceinline__ float b2f(ushortT h) {
    union { uintT u; float f; } x; x.u = ((uintT)h) << 16; return x.f;
}
__device__ __forceinline__ uintT pk2(float lo, float hi) {
    union { __hip_bfloat162 h; uintT u; } cv;
    cv.h = __float22bfloat162_rn(make_float2(lo, hi));
    return cv.u;
}
// 8 consecutive fp32 -> bf16 MFMA A-fragment (fallback path)
__device__ __forceinline__ short8 ldfrag(const float* p) {
    const float4 x = ((const float4*)p)[0];
    const float4 y = ((const float4*)p)[1];
    union { uintT u[4]; short8 s; } r;
    r.u[0] = pk2(x.x, x.y); r.u[1] = pk2(x.z, x.w);
    r.u[2] = pk2(y.x, y.y); r.u[3] = pk2(y.z, y.w);
    return r.s;
}

// ---- weight-table layout (ushort offsets within wt) ----
#define OFF_W1SO 0
#define OFF_W2SO 45056
#define OFF_W1DF 65536
#define OFF_W1G  68608
#define OFF_W1UP 70656
#define OFF_W2DF 71680
#define OFF_W2G  72704
#define OFF_W2UP 74752
#define WT_USH   75264

// ---- CSR workspace layout (bytes from ws base) ----
#define NOFF_OFF   56320000ULL
#define CUR_OFF    56360016ULL
#define WT_OFF     57040032ULL
#define WS_CSR     57190560ULL
#define NS16_OFF   57190560ULL              // bf16 node_s [10000][128]
#define WS_NS      59750560ULL
#define ES16_OFF   59750560ULL              // bf16 edge_s [160000][32]
#define WS_ES      69990560ULL

__device__ __forceinline__ bool idx_is64(const int* pi) {
    return (pi[1] | pi[3] | pi[5] | pi[7] | pi[9] | pi[11] | pi[13] | pi[15]) == 0;
}

// weight transpose helper (shared by setup_kernel and fallback prep_kernel)
__device__ __forceinline__ void weight_prep(
    int i,
    const float* __restrict__ W1so, const float* __restrict__ W2so,
    const float* __restrict__ W1d,  const float* __restrict__ W1f,
    const float* __restrict__ W1g,  const float* __restrict__ W1up,
    const float* __restrict__ W2d,  const float* __restrict__ W2f,
    const float* __restrict__ W2g,  const float* __restrict__ W2up,
    ushortT* __restrict__ ws)
{
    if (i < OFF_W2SO) {                        // W1soT [n=128][k=352], k<333 real
        int n = i / 352, k = i - n * 352;
        ws[i] = (k < 333) ? f2b(W1so[k * 128 + n]) : (ushortT)0;
    } else if (i < OFF_W1DF) {                 // W2soT [128][160], k<153 real
        int j = i - OFF_W2SO, n = j / 160, k = j - n * 160;
        ws[i] = (k < 153) ? f2b(W2so[k * 128 + n]) : (ushortT)0;
    } else if (i < OFF_W1G) {                  // W1dfT [48][64]: n<36 Wd, 36..38 Wf
        int j = i - OFF_W1DF, n = j / 64, k = j - n * 64;
        float v = 0.f;
        if (k < 36) { if (n < 36) v = W1d[k * 36 + n]; else if (n < 39) v = W1f[k * 3 + (n - 36)]; }
        ws[i] = f2b(v);
    } else if (i < OFF_W1UP) {                 // W1gT [16][128]
        int j = i - OFF_W1G, n = j / 128, k = j - n * 128;
        ws[i] = f2b(W1g[k * 16 + n]);
    } else if (i < OFF_W2DF) {                 // W1upT [16][64], k<36 real
        int j = i - OFF_W1UP, n = j / 64, k = j - n * 64;
        ws[i] = (k < 36) ? f2b(W1up[k * 16 + n]) : (ushortT)0;
    } else if (i < OFF_W2G) {                  // W2dfT [32][32]: n<16 Wd, 16..18 Wf; k<16
        int j = i - OFF_W2DF, n = j / 32, k = j - n * 32;
        float v = 0.f;
        if (k < 16) { if (n < 16) v = W2d[k * 16 + n]; else if (n < 19) v = W2f[k * 3 + (n - 16)]; }
        ws[i] = f2b(v);
    } else if (i < OFF_W2UP) {                 // W2gT [16][128]
        int j = i - OFF_W2G, n = j / 128, k = j - n * 128;
        ws[i] = f2b(W2g[k * 16 + n]);
    } else if (i < WT_USH) {                   // W2upT [16][32], k<16 real
        int j = i - OFF_W2UP, n = j / 32, k = j - n * 32;
        ws[i] = (k < 16) ? f2b(W2up[k * 16 + n]) : (ushortT)0;
    }
}

// CSR-mode combined setup: weight transpose + degree histogram + bf16 input tables.
// grid 625*256 = 160000 exactly. cur must be zeroed beforehand (memset).
__global__ __launch_bounds__(256) void setup_kernel(
    const float* __restrict__ W1so, const float* __restrict__ W2so,
    const float* __restrict__ W1d,  const float* __restrict__ W1f,
    const float* __restrict__ W1g,  const float* __restrict__ W1up,
    const float* __restrict__ W2d,  const float* __restrict__ W2f,
    const float* __restrict__ W2g,  const float* __restrict__ W2up,
    ushortT* __restrict__ ws,
    const void* __restrict__ eidx, int* __restrict__ cur,
    const float* __restrict__ node_s, const float* __restrict__ edge_s,
    ushortT* __restrict__ ns16, ushortT* __restrict__ es16)
{
    int i = blockIdx.x * 256 + threadIdx.x;
    // histogram
    {
        const int* pi = (const int*)eidx;
        const long long* pl = (const long long*)eidx;
        int r = idx_is64(pi) ? (int)pl[i] : pi[i];
        atomicAdd(&cur[r], 1);
    }
    // bf16 node_s table: 1,280,000 elems = 160,000 x 8
    if (ns16 && i < 160000) {
        float4 x = ((const float4*)node_s)[i * 2];
        float4 y = ((const float4*)node_s)[i * 2 + 1];
        uint4 st;
        st.x = pk2(x.x, x.y); st.y = pk2(x.z, x.w);
        st.z = pk2(y.x, y.y); st.w = pk2(y.z, y.w);
        ((uint4*)ns16)[i] = st;
    }
    // bf16 edge_s table: 5,120,000 elems = 160,000 x 32
    if (es16) {
        #pragma unroll
        for (int k = 0; k < 4; ++k) {
            float4 x = ((const float4*)edge_s)[i * 8 + 2 * k];
            float4 y = ((const float4*)edge_s)[i * 8 + 2 * k + 1];
            uint4 st;
            st.x = pk2(x.x, x.y); st.y = pk2(x.z, x.w);
            st.z = pk2(y.x, y.y); st.w = pk2(y.z, y.w);
            ((uint4*)es16)[i * 4 + k] = st;
        }
    }
    // weight transpose (first 75,264 threads)
    weight_prep(i, W1so, W2so, W1d, W1f, W1g, W1up, W2d, W2f, W2g, W2up, ws);
}

// fallback (non-CSR): weight transpose + zero d_out
__global__ __launch_bounds__(256) void prep_kernel(
    const float* __restrict__ W1so, const float* __restrict__ W2so,
    const float* __restrict__ W1d,  const float* __restrict__ W1f,
    const float* __restrict__ W1g,  const float* __restrict__ W1up,
    const float* __restrict__ W2d,  const float* __restrict__ W2f,
    const float* __restrict__ W2g,  const float* __restrict__ W2up,
    ushortT* __restrict__ ws, float* __restrict__ out)
{
    int i = blockIdx.x * 256 + threadIdx.x;    // grid 294*256 = 75264
    float4* o4 = (float4*)out;
    #pragma unroll
    for (int k = 0; k < 6; ++k) {
        int z = i + k * 75264;
        if (z < 440000) o4[z] = make_float4(0.f, 0.f, 0.f, 0.f);
    }
    weight_prep(i, W1so, W2so, W1d, W1f, W1g, W1up, W2d, W2f, W2g, W2up, ws);
}

// single block: exclusive scan of cur[10000] -> noff[10001]; re-zero cur.
// LDS-staged for coalesced global access.
__global__ __launch_bounds__(256) void scan_kernel(int* __restrict__ cur,
                                                   int* __restrict__ noff)
{
    __shared__ int buf[10000];
    __shared__ int partial[256];
    const int t = threadIdx.x;
    for (int i = t; i < NN; i += 256) buf[i] = cur[i];     // coalesced
    for (int i = t; i < NN; i += 256) cur[i] = 0;          // re-zero for edge alloc
    __syncthreads();
    const int base = t * 40;
    int s = 0;
    #pragma unroll
    for (int i = 0; i < 40; ++i) s += (base + i < NN) ? buf[base + i] : 0;
    partial[t] = s;
    __syncthreads();
    for (int o = 1; o < 256; o <<= 1) {
        int v = (t >= o) ? partial[t - o] : 0;
        __syncthreads();
        partial[t] += v;
        __syncthreads();
    }
    int run = (t == 0) ? 0 : partial[t - 1];
    #pragma unroll
    for (int i = 0; i < 40; ++i) {
        int gi = base + i;
        if (gi < NN) { int v = buf[gi]; noff[gi] = run; run += v; }
    }
    if (t == 255) noff[NN] = partial[255];
}

// one wave per node: FB rows are CSR-contiguous -> pure streaming read.
__global__ __launch_bounds__(256) void node_kernel(const ushortT* __restrict__ fb,
                                                   const int* __restrict__ noff,
                                                   float* __restrict__ out)
{
    const int w = threadIdx.x >> 6, l = threadIdx.x & 63;
    const int n = blockIdx.x * 4 + w;          // grid 2500 -> 10000 nodes
    if (l >= 44) return;                        // 44 lanes x 4 bf16 cols = 176
    const int s = noff[n], eend = noff[n + 1];
    float a0 = 0.f, a1 = 0.f, a2 = 0.f, a3 = 0.f;
    int idx = s;
    for (; idx + 2 <= eend; idx += 2) {
        uint2 p0 = *(const uint2*)(fb + (size_t)idx * 176 + l * 4);
        uint2 p1 = *(const uint2*)(fb + (size_t)(idx + 1) * 176 + l * 4);
        a0 += b2f((ushortT)(p0.x & 0xffff)); a1 += b2f((ushortT)(p0.x >> 16));
        a2 += b2f((ushortT)(p0.y & 0xffff)); a3 += b2f((ushortT)(p0.y >> 16));
        a0 += b2f((ushortT)(p1.x & 0xffff)); a1 += b2f((ushortT)(p1.x >> 16));
        a2 += b2f((ushortT)(p1.y & 0xffff)); a3 += b2f((ushortT)(p1.y >> 16));
    }
    if (idx < eend) {
        uint2 p0 = *(const uint2*)(fb + (size_t)idx * 176 + l * 4);
        a0 += b2f((ushortT)(p0.x & 0xffff)); a1 += b2f((ushortT)(p0.x >> 16));
        a2 += b2f((ushortT)(p0.y & 0xffff)); a3 += b2f((ushortT)(p0.y >> 16));
    }
    ((float4*)(out + (size_t)n * 176))[l] = make_float4(a0, a1, a2, a3);
}

#define MFMA(a, b, c) __builtin_amdgcn_mfma_f32_16x16x32_bf16((a), (b), (c), 0, 0, 0)

// LDS 31,232 B -> 5 blocks/CU. 8 barriers. Wave-local gates. Inline CSR slot alloc.
__global__ __launch_bounds__(256, 5) void edge_kernel(
    const float* __restrict__ node_s, const float* __restrict__ node_v,
    const float* __restrict__ edge_s, const float* __restrict__ edge_v,
    const float* __restrict__ frames,
    const float* __restrict__ b1so, const float* __restrict__ b1g,
    const float* __restrict__ b2so, const float* __restrict__ b2g,
    const float* __restrict__ attW, const float* __restrict__ attb,
    const ushortT* __restrict__ wsc,
    const void* __restrict__ eidx, float* __restrict__ out,
    ushortT* __restrict__ fb, int* __restrict__ cur, const int* __restrict__ noff,
    const ushortT* __restrict__ ns16, const ushortT* __restrict__ es16,
    int csr)
{
    const ushortT* W1T   = wsc + OFF_W1SO;
    const ushortT* W2T   = wsc + OFF_W2SO;
    const ushortT* W1dfT = wsc + OFF_W1DF;
    const ushortT* W1gT  = wsc + OFF_W1G;
    const ushortT* W1upT = wsc + OFF_W1UP;
    const ushortT* W2dfT = wsc + OFF_W2DF;
    const ushortT* W2gT  = wsc + OFF_W2G;
    const ushortT* W2upT = wsc + OFF_W2UP;

    __shared__ __align__(16) char smem[31232];
    ushortT* mvA     = (ushortT*)smem;                 // [96][40] (A->B) | m2 [32][168] (D->L)
    ushortT* m2      = (ushortT*)smem;
    ushortT* vhidA   = (ushortT*)(smem + 10752);       // [96][40] (B->E2) | s2s [32][136]
    ushortT* s2s     = (ushortT*)(smem + 10752);
    ushortT* normbuf = (ushortT*)(smem + 19456);       // [32][72] (A..C->D)
    ushortT* v1A     = (ushortT*)(smem + 19456);       // [96][24] (E->L)
    ushortT* vhid2A  = (ushortT*)(smem + 24064);       // [96][24] (G->J2/H)
    float*   vfr2f   = (float*)(smem + 28672);         // [96][3]  (G->H)
    float*   fr      = (float*)(smem + 29824);         // [32][9]
    float*   attn    = (float*)(smem + 30976);         // [32]
    int*     eposb   = (int*)(smem + 31104);           // [32]

    const int t  = threadIdx.x;
    const int eg = blockIdx.x * EPB;
    const int w  = t >> 6, lane = t & 63, lq = lane >> 4, ln = lane & 15;
    const int te = t >> 3, tj = t & 7;     // 8 threads per edge
    const int p  = w & 1;

    const int* pi = (const int*)eidx;
    const long long* pl = (const long long*)eidx;
    const bool is64 = idx_is64(pi);

    // ==== Phase A: gathers (12-elem chunks: 3 float4 -> 6 packed uint) ====
    {
        const int nr = is64 ? (int)pl[eg + te] : pi[eg + te];
        const int nc = is64 ? (int)pl[E_TOT + eg + te] : pi[E_TOT + eg + te];
        #pragma unroll
        for (int mi = 0; mi < 2; ++mi) {
            if (mi == 1 && tj != 0) break;
            int m = (mi == 0) ? tj : 8;        // chunks 0..8; chunk = 4 c-cols x 3 sp
            const float* src;
            if (m < 4)       src = node_v + nr * 48 + 12 * m;
            else if (m == 4) src = edge_v + (eg + te) * 12;
            else             src = node_v + nc * 48 + 12 * (m - 5);
            float4 x = ((const float4*)src)[0];
            float4 y = ((const float4*)src)[1];
            float4 z = ((const float4*)src)[2];
            float v[12] = {x.x, x.y, x.z, x.w, y.x, y.y, y.z, y.w, z.x, z.y, z.z, z.w};
            int c0 = 4 * m;
            #pragma unroll
            for (int sp = 0; sp < 3; ++sp) {
                *(uintT*)(mvA + (sp * 32 + te) * 40 + c0)     = pk2(v[sp],     v[3 + sp]);
                *(uintT*)(mvA + (sp * 32 + te) * 40 + c0 + 2) = pk2(v[6 + sp], v[9 + sp]);
            }
        }
        #pragma unroll
        for (int k = 0; k < 2; ++k) {           // frames: 9 per edge
            int j = tj + k * 8;
            if (j < 9) fr[te * 9 + j] = frames[(eg + te) * 9 + j];
        }
        #pragma unroll
        for (int k = 0; k < 3; ++k) {           // normbuf cols 45..63 = 0
            int c = 45 + tj + k * 8;
            if (c < 64) normbuf[te * 72 + c] = 0;
        }
        if (t < 192) {                          // mvA cols 36..39 = 0
            int r = t >> 1, cc = 36 + ((t & 1) << 1);
            *(uintT*)(mvA + r * 40 + cc) = 0;
        }
    }
    __syncthreads();   // (1)

    // ==== Phase B: mvA[96xK36] @ W1dfT[48][64] -> vhidA[96][<=40] ====
    for (int u = w; u < 18; u += 4) {
        int mt = u / 3, nt = u - mt * 3;
        const ushortT* ap = mvA + (mt * 16 + ln) * 40 + lq * 8;
        const ushortT* bp = W1dfT + (nt * 16 + ln) * 64 + lq * 8;
        f32x4 acc = {0.f, 0.f, 0.f, 0.f};
        acc = MFMA(*(const short8*)ap, *(const short8*)bp, acc);
        short8 a2 = {0, 0, 0, 0, 0, 0, 0, 0};
        if (lq == 0) a2 = *(const short8*)(ap + 32);
        acc = MFMA(a2, *(const short8*)(bp + 32), acc);
        if (nt < 2 || ln < 8) {
            ushortT* op = vhidA + (mt * 16 + lq * 4) * 40 + nt * 16 + ln;
            op[0]   = f2b(acc[0]); op[40]  = f2b(acc[1]);
            op[80]  = f2b(acc[2]); op[120] = f2b(acc[3]);
        }
    }
    __syncthreads();   // (2)

    // ==== Phase C: v_norm1 + local1 -> normbuf cols 0..44 ====
    {
        #pragma unroll
        for (int k = 0; k < 5; ++k) {
            int h = tj + k * 8;
            if (h < 36) {
                float a0 = b2f(vhidA[te * 40 + h]);
                float a1 = b2f(vhidA[(32 + te) * 40 + h]);
                float a2 = b2f(vhidA[(64 + te) * 40 + h]);
                normbuf[te * 72 + h] = f2b(sqrtf(fmaf(a0, a0, fmaf(a1, a1, fmaf(a2, a2, 1e-8f)))));
            }
        }
        for (int i = t; i < 288; i += 256) {
            int e = i / 9, r = i - e * 9, a = r / 3, b = r - a * 3;
            float x = fr[e * 9 + b * 3 + 0] * b2f(vhidA[e * 40 + 36 + a])
                    + fr[e * 9 + b * 3 + 1] * b2f(vhidA[(32 + e) * 40 + 36 + a])
                    + fr[e * 9 + b * 3 + 2] * b2f(vhidA[(64 + e) * 40 + 36 + a]);
            normbuf[e * 72 + 36 + r] = f2b(x);
        }
    }
    __syncthreads();   // (3)

    // ==== Phase D: s_out1 — A from bf16 tables (or fp32 fallback) + normbuf ====
    {
        const int klq = lq * 8;
        const int e0 = ln, e1 = 16 + ln;
        int r0, c0, r1, c1;
        if (is64) {
            r0 = (int)pl[eg + e0]; r1 = (int)pl[eg + e1];
            c0 = (int)pl[E_TOT + eg + e0]; c1 = (int)pl[E_TOT + eg + e1];
        } else {
            r0 = pi[eg + e0]; r1 = pi[eg + e1];
            c0 = pi[E_TOT + eg + e0]; c1 = pi[E_TOT + eg + e1];
        }
        r0 *= 128; c0 *= 128; r1 *= 128; c1 *= 128;
        const int eb0 = (eg + e0) * 32, eb1 = (eg + e1) * 32;
        f32x4 acc00 = {0,0,0,0}, acc01 = {0,0,0,0}, acc10 = {0,0,0,0}, acc11 = {0,0,0,0};
        const ushortT* b0p = W1T + (w * 32 + ln) * 352 + klq;
        const ushortT* b1p = W1T + (w * 32 + 16 + ln) * 352 + klq;
        #pragma unroll
        for (int ks = 0; ks < 9; ++ks) {
            short8 a0, a1;
            if (ks < 4) {
                if (ns16) {
                    a0 = *(const short8*)(ns16 + r0 + ks * 32 + klq);
                    a1 = *(const short8*)(ns16 + r1 + ks * 32 + klq);
                } else {
                    a0 = ldfrag(node_s + r0 + ks * 32 + klq);
                    a1 = ldfrag(node_s + r1 + ks * 32 + klq);
                }
            } else if (ks == 4) {
                if (es16) {
                    a0 = *(const short8*)(es16 + eb0 + klq);
                    a1 = *(const short8*)(es16 + eb1 + klq);
                } else {
                    a0 = ldfrag(edge_s + eb0 + klq);
                    a1 = ldfrag(edge_s + eb1 + klq);
                }
            } else {
                if (ns16) {
                    a0 = *(const short8*)(ns16 + c0 + (ks - 5) * 32 + klq);
                    a1 = *(const short8*)(ns16 + c1 + (ks - 5) * 32 + klq);
                } else {
                    a0 = ldfrag(node_s + c0 + (ks - 5) * 32 + klq);
                    a1 = ldfrag(node_s + c1 + (ks - 5) * 32 + klq);
                }
            }
            short8 b0 = *(const short8*)(b0p + ks * 32);
            short8 b1 = *(const short8*)(b1p + ks * 32);
            acc00 = MFMA(a0, b0, acc00); acc01 = MFMA(a0, b1, acc01);
            acc10 = MFMA(a1, b0, acc10); acc11 = MFMA(a1, b1, acc11);
        }
        #pragma unroll
        for (int ks = 9; ks < 11; ++ks) {
            short8 a0 = *(const short8*)(normbuf + e0 * 72 + (ks - 9) * 32 + klq);
            short8 a1 = *(const short8*)(normbuf + e1 * 72 + (ks - 9) * 32 + klq);
            short8 b0 = *(const short8*)(b0p + ks * 32);
            short8 b1 = *(const short8*)(b1p + ks * 32);
            acc00 = MFMA(a0, b0, acc00); acc01 = MFMA(a0, b1, acc01);
            acc10 = MFMA(a1, b0, acc10); acc11 = MFMA(a1, b1, acc11);
        }
        const int n0 = w * 32 + ln, n1 = n0 + 16;
        float bi0 = b1so[n0], bi1 = b1so[n1];
        #pragma unroll
        for (int r = 0; r < 4; ++r) {
            int m0 = lq * 4 + r;
            m2[m0 * 168 + n0]        = f2b(siluf_(acc00[r] + bi0));
            m2[m0 * 168 + n1]        = f2b(siluf_(acc01[r] + bi1));
            m2[(16 + m0) * 168 + n0] = f2b(siluf_(acc10[r] + bi0));
            m2[(16 + m0) * 168 + n1] = f2b(siluf_(acc11[r] + bi1));
        }
    }
    __syncthreads();   // (4)

    // ==== Phase E+G (wave-local) ====
    {
        f32x4 gacc = {0,0,0,0};
        {
            const ushortT* ap = m2 + (p * 16 + ln) * 168;
            const ushortT* bp = W1gT + ln * 128;
            #pragma unroll
            for (int ks = 0; ks < 4; ++ks)
                gacc = MFMA(*(const short8*)(ap + ks * 32 + lq * 8),
                            *(const short8*)(bp + ks * 32 + lq * 8), gacc);
        }
        float g1[4];
        {
            float bi = b1g[ln];
            #pragma unroll
            for (int r = 0; r < 4; ++r) g1[r] = sigmoidf_(gacc[r] + bi);
        }
        const ushortT* bpu = W1upT + ln * 64 + lq * 8;
        short8 bu1 = *(const short8*)bpu;
        short8 bu2 = *(const short8*)(bpu + 32);
        #pragma unroll
        for (int c = 0; c < 2; ++c) {
            if (c == 1 && w >= 2) break;
            int mt = w + c * 4;
            const ushortT* ap = vhidA + (mt * 16 + ln) * 40 + lq * 8;
            f32x4 acc = {0,0,0,0};
            acc = MFMA(*(const short8*)ap, bu1, acc);
            short8 a2 = {0, 0, 0, 0, 0, 0, 0, 0};
            if (lq == 0) a2 = *(const short8*)(ap + 32);
            acc = MFMA(a2, bu2, acc);
            #pragma unroll
            for (int r = 0; r < 4; ++r) {
                int row = mt * 16 + lq * 4 + r;
                v1A[row * 24 + ln] = f2b(acc[r] * g1[r]);
            }
        }
        #pragma unroll
        for (int c = 0; c < 2; ++c) {
            if (c == 1 && w >= 2) break;
            int mt = w + c * 4;
            const ushortT* ap = v1A + (mt * 16 + ln) * 24 + lq * 8;
            short8 a = {0, 0, 0, 0, 0, 0, 0, 0};
            if (lq < 2) a = *(const short8*)ap;
            #pragma unroll
            for (int nt = 0; nt < 2; ++nt) {
                const ushortT* bp = W2dfT + (nt * 16 + ln) * 32 + lq * 8;
                f32x4 acc = {0,0,0,0};
                acc = MFMA(a, *(const short8*)bp, acc);
                if (nt == 0) {
                    ushortT* op = vhid2A + (mt * 16 + lq * 4) * 24 + ln;
                    op[0]  = f2b(acc[0]); op[24] = f2b(acc[1]);
                    op[48] = f2b(acc[2]); op[72] = f2b(acc[3]);
                } else if (ln < 3) {
                    float* op = vfr2f + (mt * 16 + lq * 4) * 3 + ln;
                    op[0] = acc[0]; op[3] = acc[1]; op[6] = acc[2]; op[9] = acc[3];
                }
            }
        }
    }
    __syncthreads();   // (5)

    // ==== Phase H: norm2 + local2 + zero pad into m2 cols 128..159 ====
    {
        #pragma unroll
        for (int k = 0; k < 2; ++k) {
            int i = t + k * 256, e = i >> 4, h = i & 15;
            float a0 = b2f(vhid2A[e * 24 + h]);
            float a1 = b2f(vhid2A[(32 + e) * 24 + h]);
            float a2 = b2f(vhid2A[(64 + e) * 24 + h]);
            m2[e * 168 + 128 + h] = f2b(sqrtf(fmaf(a0, a0, fmaf(a1, a1, fmaf(a2, a2, 1e-8f)))));
        }
        for (int i = t; i < 288; i += 256) {
            int e = i / 9, r = i - e * 9, a = r / 3, b = r - a * 3;
            float x = fr[e * 9 + b * 3 + 0] * vfr2f[e * 3 + a]
                    + fr[e * 9 + b * 3 + 1] * vfr2f[(32 + e) * 3 + a]
                    + fr[e * 9 + b * 3 + 2] * vfr2f[(64 + e) * 3 + a];
            m2[e * 168 + 144 + r] = f2b(x);
        }
        if (tj) m2[te * 168 + 152 + tj] = 0;
    }
    __syncthreads();   // (6)

    // ==== Phase I: s_out2 = m2[32][160] @ W2soT -> s2s (silu) ====
    {
        f32x4 acc00 = {0,0,0,0}, acc01 = {0,0,0,0}, acc10 = {0,0,0,0}, acc11 = {0,0,0,0};
        const ushortT* a0p = m2 + ln * 168 + lq * 8;
        const ushortT* a1p = m2 + (16 + ln) * 168 + lq * 8;
        const ushortT* b0p = W2T + (w * 32 + ln) * 160 + lq * 8;
        const ushortT* b1p = W2T + (w * 32 + 16 + ln) * 160 + lq * 8;
        #pragma unroll
        for (int ks = 0; ks < 5; ++ks) {
            short8 a0 = *(const short8*)(a0p + ks * 32);
            short8 a1 = *(const short8*)(a1p + ks * 32);
            short8 b0 = *(const short8*)(b0p + ks * 32);
            short8 b1 = *(const short8*)(b1p + ks * 32);
            acc00 = MFMA(a0, b0, acc00); acc01 = MFMA(a0, b1, acc01);
            acc10 = MFMA(a1, b0, acc10); acc11 = MFMA(a1, b1, acc11);
        }
        const int n0 = w * 32 + ln, n1 = n0 + 16;
        float bi0 = b2so[n0], bi1 = b2so[n1];
        #pragma unroll
        for (int r = 0; r < 4; ++r) {
            int m0 = lq * 4 + r;
            s2s[m0 * 136 + n0]        = f2b(siluf_(acc00[r] + bi0));
            s2s[m0 * 136 + n1]        = f2b(siluf_(acc01[r] + bi1));
            s2s[(16 + m0) * 136 + n0] = f2b(siluf_(acc10[r] + bi0));
            s2s[(16 + m0) * 136 + n1] = f2b(siluf_(acc11[r] + bi1));
        }
    }
    __syncthreads();   // (7)

    // ==== Phase J (wave-local) + attention + CSR slot allocation ====
    {
        f32x4 gacc = {0,0,0,0};
        {
            const ushortT* ap = s2s + (p * 16 + ln) * 136;
            const ushortT* bp = W2gT + ln * 128;
            #pragma unroll
            for (int ks = 0; ks < 4; ++ks)
                gacc = MFMA(*(const short8*)(ap + ks * 32 + lq * 8),
                            *(const short8*)(bp + ks * 32 + lq * 8), gacc);
        }
        float g2[4];
        {
            float bi = b2g[ln];
            #pragma unroll
            for (int r = 0; r < 4; ++r) g2[r] = sigmoidf_(gacc[r] + bi);
        }
        const ushortT* bpu = W2upT + ln * 32 + lq * 8;
        short8 bu = *(const short8*)bpu;
        #pragma unroll
        for (int c = 0; c < 2; ++c) {
            if (c == 1 && w >= 2) break;
            int mt = w + c * 4;
            const ushortT* ap = vhid2A + (mt * 16 + ln) * 24 + lq * 8;
            short8 a = {0, 0, 0, 0, 0, 0, 0, 0};
            if (lq < 2) a = *(const short8*)ap;
            f32x4 acc = {0,0,0,0};
            acc = MFMA(a, bu, acc);
            #pragma unroll
            for (int r = 0; r < 4; ++r) {
                int row = mt * 16 + lq * 4 + r;
                float vfin = b2f(v1A[row * 24 + ln]) + acc[r] * g2[r];
                v1A[row * 24 + ln] = f2b(vfin);
            }
        }
        {
            float sum = 0.f;
            int c0 = tj * 16;
            #pragma unroll
            for (int c = c0; c < c0 + 16; ++c)
                sum = fmaf(b2f(m2[te * 168 + c]) + b2f(s2s[te * 136 + c]), attW[c], sum);
            sum += __shfl_xor(sum, 4);
            sum += __shfl_xor(sum, 2);
            sum += __shfl_xor(sum, 1);
            if (tj == 0) attn[te] = sigmoidf_(sum + attb[0]);
        }
        if (csr && tj == 0) {   // allocate this edge's CSR slot (order-free)
            int nr = is64 ? (int)pl[eg + te] : pi[eg + te];
            int pos = atomicAdd(&cur[nr], 1);
            eposb[te] = noff[nr] + pos;
        }
    }
    __syncthreads();   // (8)

    // ==== Phase L: per-edge output ====
    {
        const float at = attn[te];
        if (csr) {
            const int pos = eposb[te];
            ushortT* fbe = fb + (size_t)pos * 176;
            #pragma unroll
            for (int k = 0; k < 11; ++k) {
                int j = 2 * tj + 16 * k;
                float v0, v1;
                if (j < 128) {
                    v0 = (b2f(m2[te * 168 + j])     + b2f(s2s[te * 136 + j]))     * at;
                    v1 = (b2f(m2[te * 168 + j + 1]) + b2f(s2s[te * 136 + j + 1])) * at;
                } else {
                    int r = j - 128;
                    int o0 = r / 3,        sp0 = r - o0 * 3;
                    int o1 = (r + 1) / 3,  sp1 = (r + 1) - o1 * 3;
                    v0 = b2f(v1A[(sp0 * 32 + te) * 24 + o0]);
                    v1 = b2f(v1A[(sp1 * 32 + te) * 24 + o1]);
                }
                *(uintT*)(fbe + j) = pk2(v0, v1);
            }
        } else {
            const int nr = is64 ? (int)pl[eg + te] : pi[eg + te];
            const int orow = nr * 176;
            #pragma unroll
            for (int k = 0; k < 22; ++k) {
                int j = tj + k * 8;
                float val;
                if (j < 128) {
                    val = (b2f(m2[te * 168 + j]) + b2f(s2s[te * 136 + j])) * at;
                } else {
                    int r = j - 128, o = r / 3, sp = r - o * 3;
                    val = b2f(v1A[(sp * 32 + te) * 24 + o]);
                }
                atomicAdd(&out[orow + j], val);
            }
        }
    }
}

extern "C" void kernel_launch(void* const* d_in, const int* in_sizes, int n_in,
                              void* d_out, int out_size, void* d_ws, size_t ws_size,
                              hipStream_t stream) {
    const float* node_s = (const float*)d_in[0];
    const float* node_v = (const float*)d_in[1];
    const float* edge_s = (const float*)d_in[2];
    const float* edge_v = (const float*)d_in[3];
    const float* frames = (const float*)d_in[4];
    const float* W1d  = (const float*)d_in[5];
    const float* W1f  = (const float*)d_in[6];
    const float* W1so = (const float*)d_in[7];
    const float* b1so = (const float*)d_in[8];
    const float* W1up = (const float*)d_in[9];
    const float* W1g  = (const float*)d_in[10];
    const float* b1g  = (const float*)d_in[11];
    const float* W2d  = (const float*)d_in[12];
    const float* W2f  = (const float*)d_in[13];
    const float* W2so = (const float*)d_in[14];
    const float* b2so = (const float*)d_in[15];
    const float* W2up = (const float*)d_in[16];
    const float* W2g  = (const float*)d_in[17];
    const float* b2g  = (const float*)d_in[18];
    const float* attW = (const float*)d_in[19];
    const float* attb = (const float*)d_in[20];
    const void*  eidx = d_in[21];

    float* out = (float*)d_out;
    char* ws = (char*)d_ws;

    int mode = 0;
    if (ws_size >= WS_ES)       mode = 3;
    else if (ws_size >= WS_NS)  mode = 2;
    else if (ws_size >= WS_CSR) mode = 1;
    const int csr = (mode >= 1);

    ushortT* wt    = csr ? (ushortT*)(ws + WT_OFF)  : (ushortT*)ws;
    ushortT* fbuf  = csr ? (ushortT*)ws             : nullptr;
    int*     noff  = csr ? (int*)(ws + NOFF_OFF)    : nullptr;
    int*     cur   = csr ? (int*)(ws + CUR_OFF)     : nullptr;
    ushortT* ns16  = (mode >= 2) ? (ushortT*)(ws + NS16_OFF) : nullptr;
    ushortT* es16  = (mode >= 3) ? (ushortT*)(ws + ES16_OFF) : nullptr;

    if (csr) {
        hipMemsetAsync(cur, 0, NN * sizeof(int), stream);
        setup_kernel<<<625, 256, 0, stream>>>(
            W1so, W2so, W1d, W1f, W1g, W1up, W2d, W2f, W2g, W2up,
            wt, eidx, cur, node_s, edge_s, ns16, es16);
        scan_kernel<<<1, 256, 0, stream>>>(cur, noff);
    } else {
        prep_kernel<<<294, 256, 0, stream>>>(W1so, W2so, W1d, W1f, W1g, W1up,
                                             W2d, W2f, W2g, W2up, wt, out);
    }

    edge_kernel<<<E_TOT / EPB, 256, 0, stream>>>(
        node_s, node_v, edge_s, edge_v, frames,
        b1so, b1g, b2so, b2g, attW, attb,
        (const ushortT*)wt, eidx, out, fbuf, cur, noff, ns16, es16, csr);

    if (csr) {
        node_kernel<<<2500, 256, 0, stream>>>((const ushortT*)fbuf, noff, out);
    }
}